// Round 7
// baseline (1416.778 us; speedup 1.0000x reference)
//
#include <hip/hip_runtime.h>
#include <hip/hip_bf16.h>

// HANConv (HANModel). R7: (1) wave-independent 16-row strips in all MFMA
// kernels (proj/colsum/linW/author) — 4x independent memory streams/block,
// no per-strip sync (R6 counters: proj occupancy 20%, MfmaUtil 2.2% =
// latency-bound); (2) compute_a4 reads h_p once for all 4 paper logit sets;
// (3) CSR builds merged across the 3 edge types (hist3/reorder3, per-type
// buffers) so scattered-atomic latency tails overlap. Gather unchanged.

#define HEADS 4
#define DH 32
#define HID 128
#define IN_F 128
#define OUT_F 64
#define NEG 0.2f

typedef unsigned short u16;
typedef unsigned int u32;
typedef __attribute__((ext_vector_type(8))) short short8;
typedef __attribute__((ext_vector_type(4))) float f32x4;

__device__ __forceinline__ float us2f(u16 u){ return __uint_as_float(((u32)u) << 16); }
__device__ __forceinline__ u16 f2us(float f){            // f32 -> bf16 RNE
  u32 u = __float_as_uint(f);
  u += 0x7fffu + ((u >> 16) & 1u);
  return (u16)(u >> 16);
}
__device__ __forceinline__ float fin(float v){ return (fabsf(v) < 1e30f) ? v : 0.f; }
__device__ __forceinline__ u16 san16(u16 r){ return (((r >> 7) & 0xff) == 0xff) ? (u16)0 : r; }
// fast tanh via exp2-backed __expf; clamp keeps (t-1)/(t+1) finite.
__device__ __forceinline__ float ftanh(float x){
  float t = __expf(fminf(fmaxf(2.f * x, -30.f), 30.f));
  return __fdividef(t - 1.f, t + 1.f);
}
// width-adaptive sanitized loads from raw input tensors
__device__ __forceinline__ float ldf(const void* p, size_t i, int wide){
  float v = wide ? ((const float*)p)[i] : us2f(((const u16*)p)[i]);
  return fin(v);
}
__device__ __forceinline__ u16 ld16(const void* p, size_t i, int wide){
  if (wide) return f2us(fin(((const float*)p)[i]));
  return san16(((const u16*)p)[i]);
}
__device__ __forceinline__ int ld_idx(const int* __restrict__ p, int e, int sh, int n){
  int v = p[(size_t)e << sh];
  return v < 0 ? 0 : (v >= n ? n - 1 : v);
}

// ---- detection kernels -----------------------------------------------------
__global__ void detect_float_width(const u16* __restrict__ x, int n, int* __restrict__ flag)
{
  __shared__ int cnt;
  if (threadIdx.x == 0) cnt = 0;
  __syncthreads();
  int local = 0;
  for (int i = threadIdx.x; i < n; i += blockDim.x) {
    int e = (x[i] >> 7) & 0xff;
    if (e == 0 || (e >= 100 && e <= 150)) local++;
  }
  atomicAdd(&cnt, local);
  __syncthreads();
  if (threadIdx.x == 0) *flag = (cnt < (n * 9) / 10) ? 1 : 0;  // 1 = f32
}
__global__ void detect_idx_width(const int* __restrict__ s, int n, int* __restrict__ flag)
{
  __shared__ int any;
  if (threadIdx.x == 0) any = 0;
  __syncthreads();
  for (int i = threadIdx.x; i < n; i += blockDim.x)
    if (s[2 * i + 1] != 0) atomicOr(&any, 1);
  __syncthreads();
  if (threadIdx.x == 0) *flag = any ? 0 : 1;                   // 1 = int64
}

// ---- MFMA GEMM infrastructure ---------------------------------------------
// B staged transposed in LDS: Bt[c][k] bf16, row stride 256B, XOR-swizzle
// byte ^= (c&7)<<4 so 16-lane column-slice ds_read_b128 is ~conflict-free.
template<int NC>
__device__ __forceinline__ void stage_B1(const void* W1, int wide, u16* Bt)
{
  for (int i = threadIdx.x; i < 128 * NC; i += 256) {
    int k = i / NC, c = i - k * NC;
    u16 v = ld16(W1, (size_t)k * NC + c, wide);
    u32 boff = ((u32)c << 8) + (((u32)(k << 1)) ^ (((u32)(c & 7)) << 4));
    *(u16*)((char*)Bt + boff) = v;
  }
}

// B fragment for tile t, k-step kk: lane c=(t*16+(l&15)), 8 bf16 k-contiguous
__device__ __forceinline__ short8 ldsB(const u16* Bt, int t, int lane, int kk)
{
  const int c = (t << 4) + (lane & 15);
  const u32 boff = ((u32)c << 8) +
      (((u32)(((lane >> 4) << 4) + (kk << 6))) ^ (((u32)(c & 7)) << 4));
  return *(const short8*)((const char*)Bt + boff);
}

// A fragment from raw input x (runtime f32/bf16), row rb, 8 k-contiguous bf16
__device__ __forceinline__ short8 ldA_x(const void* x, size_t rb, int kg, int kk, int wide)
{
  short8 v;
  const size_t base = rb + (size_t)(kg * 8 + kk * 32);
  if (wide) {
    const float* p = (const float*)x + base;
    const float4 f0 = *(const float4*)p;
    const float4 f1 = *(const float4*)(p + 4);
    v[0] = (short)f2us(fin(f0.x)); v[1] = (short)f2us(fin(f0.y));
    v[2] = (short)f2us(fin(f0.z)); v[3] = (short)f2us(fin(f0.w));
    v[4] = (short)f2us(fin(f1.x)); v[5] = (short)f2us(fin(f1.y));
    v[6] = (short)f2us(fin(f1.z)); v[7] = (short)f2us(fin(f1.w));
  } else {
    const short8 raw = *(const short8*)((const u16*)x + base);
#pragma unroll
    for (int j = 0; j < 8; ++j) v[j] = (short)san16((u16)raw[j]);
  }
  return v;
}

// A fragment from our clean bf16 o buffer
__device__ __forceinline__ short8 ldA_o(const u16* o, size_t rb, int kg, int kk)
{
  return *(const short8*)(o + rb + (size_t)(kg * 8 + kk * 32));
}

// ---- projection: h[n,c] = bf16(x[n,:] @ W[:,c] + b[c]) ---------------------
// One wave per 16-row strip; waves grid-stride independently (no per-strip
// sync). Block stages B once.
__global__ __launch_bounds__(256, 2) void proj_mfma(
    const void* __restrict__ x, const void* __restrict__ W,
    const void* __restrict__ b, u16* __restrict__ h, int N,
    const int* __restrict__ flag_f)
{
  const int wide = *flag_f;
  __shared__ u16 Bt[128 * 128];   // 32 KB
  stage_B1<HID>(W, wide, Bt);
  __syncthreads();
  const int lane = threadIdx.x & 63;
  const int r16 = lane & 15, kg = lane >> 4;
  const int wid = (blockIdx.x << 2) + (threadIdx.x >> 6);
  const int nw = gridDim.x << 2;
  float bv[8];
#pragma unroll
  for (int t = 0; t < 8; ++t) bv[t] = ldf(b, (t << 4) + r16, wide);
  const int nstrips = (N + 15) >> 4;
  for (int sidx = wid; sidx < nstrips; sidx += nw) {
    const int rowbase = sidx << 4;
    int arow = rowbase + r16;
    if (arow >= N) arow = N - 1;
    const size_t rb = (size_t)arow * IN_F;
    f32x4 acc[8];
#pragma unroll
    for (int t = 0; t < 8; ++t) acc[t] = (f32x4){0.f, 0.f, 0.f, 0.f};
#pragma unroll
    for (int kk = 0; kk < 4; ++kk) {
      const short8 a = ldA_x(x, rb, kg, kk, wide);
#pragma unroll
      for (int t = 0; t < 8; ++t)
        acc[t] = __builtin_amdgcn_mfma_f32_16x16x32_bf16(a, ldsB(Bt, t, lane, kk), acc[t], 0, 0, 0);
    }
#pragma unroll
    for (int t = 0; t < 8; ++t) {
      const int col = (t << 4) + r16;
#pragma unroll
      for (int j = 0; j < 4; ++j) {
        const int row = rowbase + (kg << 2) + j;
        if (row < N) h[(size_t)row * HID + col] = f2us(acc[t][j] + bv[t]);
      }
    }
  }
}

// ---- colsum: S[c] += sum_n ftanh(o(relu'd bf16) @ Wk + bk) -----------------
__global__ __launch_bounds__(256, 2) void colsum_mfma(
    const u16* __restrict__ o, int rows, const void* __restrict__ Wk,
    const void* __restrict__ bk, float* __restrict__ S,
    const int* __restrict__ flag_f)
{
  const int wide = *flag_f;
  __shared__ u16 Bt[128 * 128];   // 32 KB
  __shared__ float sred[4][HID];  // 2 KB
  stage_B1<HID>(Wk, wide, Bt);
  __syncthreads();
  const int w = threadIdx.x >> 6, lane = threadIdx.x & 63;
  const int r16 = lane & 15, kg = lane >> 4;
  const int wid = (blockIdx.x << 2) + w;
  const int nw = gridDim.x << 2;
  float bkv[8];
#pragma unroll
  for (int t = 0; t < 8; ++t) bkv[t] = ldf(bk, (t << 4) + r16, wide);
  float scs[8] = {0.f, 0.f, 0.f, 0.f, 0.f, 0.f, 0.f, 0.f};
  const int nstrips = (rows + 15) >> 4;
  for (int sidx = wid; sidx < nstrips; sidx += nw) {
    const int rowbase = sidx << 4;
    int arow = rowbase + r16;
    if (arow >= rows) arow = rows - 1;
    const size_t rb = (size_t)arow * HID;
    f32x4 acc[8];
#pragma unroll
    for (int t = 0; t < 8; ++t) acc[t] = (f32x4){0.f, 0.f, 0.f, 0.f};
#pragma unroll
    for (int kk = 0; kk < 4; ++kk) {
      const short8 a = ldA_o(o, rb, kg, kk);
#pragma unroll
      for (int t = 0; t < 8; ++t)
        acc[t] = __builtin_amdgcn_mfma_f32_16x16x32_bf16(a, ldsB(Bt, t, lane, kk), acc[t], 0, 0, 0);
    }
#pragma unroll
    for (int t = 0; t < 8; ++t) {
#pragma unroll
      for (int j = 0; j < 4; ++j) {
        const int row = rowbase + (kg << 2) + j;
        if (row < rows) scs[t] += ftanh(acc[t][j] + bkv[t]);
      }
    }
  }
  // reduce: kg-groups share a column -> shfl over kg -> per-wave row -> atomic
#pragma unroll
  for (int t = 0; t < 8; ++t) {
    float v = scs[t];
    v += __shfl_xor(v, 16);
    v += __shfl_xor(v, 32);
    if (kg == 0) sred[w][(t << 4) + r16] = v;
  }
  __syncthreads();
  if (threadIdx.x < HID) {
    float v = sred[0][threadIdx.x] + sred[1][threadIdx.x] +
              sred[2][threadIdx.x] + sred[3][threadIdx.x];
    atomicAdd(&S[threadIdx.x], v);
  }
}

// ---- P = o(relu'd bf16) @ Wlin  (no bias) -> bf16 --------------------------
__global__ __launch_bounds__(256, 2) void linW_mfma(
    const u16* __restrict__ o, int rows, const void* __restrict__ Wlin,
    u16* __restrict__ P, const int* __restrict__ flag_f)
{
  const int wide = *flag_f;
  __shared__ u16 Bt[64 * 128];    // 16 KB
  stage_B1<OUT_F>(Wlin, wide, Bt);
  __syncthreads();
  const int lane = threadIdx.x & 63;
  const int r16 = lane & 15, kg = lane >> 4;
  const int wid = (blockIdx.x << 2) + (threadIdx.x >> 6);
  const int nw = gridDim.x << 2;
  const int nstrips = (rows + 15) >> 4;
  for (int sidx = wid; sidx < nstrips; sidx += nw) {
    const int rowbase = sidx << 4;
    int arow = rowbase + r16;
    if (arow >= rows) arow = rows - 1;
    const size_t rb = (size_t)arow * HID;
    f32x4 acc[4];
#pragma unroll
    for (int t = 0; t < 4; ++t) acc[t] = (f32x4){0.f, 0.f, 0.f, 0.f};
#pragma unroll
    for (int kk = 0; kk < 4; ++kk) {
      const short8 a = ldA_o(o, rb, kg, kk);
#pragma unroll
      for (int t = 0; t < 4; ++t)
        acc[t] = __builtin_amdgcn_mfma_f32_16x16x32_bf16(a, ldsB(Bt, t, lane, kk), acc[t], 0, 0, 0);
    }
#pragma unroll
    for (int t = 0; t < 4; ++t) {
      const int col = (t << 4) + r16;
#pragma unroll
      for (int j = 0; j < 4; ++j) {
        const int row = rowbase + (kg << 2) + j;
        if (row < rows) P[(size_t)row * OUT_F + col] = f2us(acc[t][j]);
      }
    }
  }
}

// ---- author out: y = o(bf16,relu'd) @ Wlin + blin  (width-adaptive) --------
__global__ __launch_bounds__(256, 2) void author_mfma(
    const u16* __restrict__ o, int rows, int node0,
    const void* __restrict__ Wlin, const void* __restrict__ blin,
    void* __restrict__ out, const int* __restrict__ flag_f)
{
  const int wide = *flag_f;
  __shared__ u16 Bt[64 * 128];    // 16 KB
  stage_B1<OUT_F>(Wlin, wide, Bt);
  __syncthreads();
  const int lane = threadIdx.x & 63;
  const int r16 = lane & 15, kg = lane >> 4;
  const int wid = (blockIdx.x << 2) + (threadIdx.x >> 6);
  const int nw = gridDim.x << 2;
  float bv[4];
#pragma unroll
  for (int t = 0; t < 4; ++t) bv[t] = ldf(blin, (t << 4) + r16, wide);
  const int nstrips = (rows + 15) >> 4;
  for (int sidx = wid; sidx < nstrips; sidx += nw) {
    const int rowbase = sidx << 4;
    int arow = rowbase + r16;
    if (arow >= rows) arow = rows - 1;
    const size_t rb = (size_t)arow * HID;
    f32x4 acc[4];
#pragma unroll
    for (int t = 0; t < 4; ++t) acc[t] = (f32x4){0.f, 0.f, 0.f, 0.f};
#pragma unroll
    for (int kk = 0; kk < 4; ++kk) {
      const short8 a = ldA_o(o, rb, kg, kk);
#pragma unroll
      for (int t = 0; t < 4; ++t)
        acc[t] = __builtin_amdgcn_mfma_f32_16x16x32_bf16(a, ldsB(Bt, t, lane, kk), acc[t], 0, 0, 0);
    }
#pragma unroll
    for (int t = 0; t < 4; ++t) {
      const int col = (t << 4) + r16;
#pragma unroll
      for (int j = 0; j < 4; ++j) {
        const int row = rowbase + (kg << 2) + j;
        if (row < rows) {
          const float val = acc[t][j] + bv[t];
          const size_t oi = (size_t)(node0 + row) * OUT_F + col;
          if (wide) ((float*)out)[oi] = val;
          else      ((u16*)out)[oi] = f2us(val);
        }
      }
    }
  }
}

// ---- per-node logits: 2 att vectors (author h) -----------------------------
__global__ __launch_bounds__(256) void compute_a2(
    const u16* __restrict__ h, const void* __restrict__ att1,
    const void* __restrict__ att2, float* __restrict__ a1,
    float* __restrict__ a2, int N, const int* __restrict__ flag_f)
{
  const int wide = *flag_f;
  __shared__ float s1[HID], s2[HID];
  if (threadIdx.x < HID) {
    s1[threadIdx.x] = ldf(att1, threadIdx.x, wide);
    s2[threadIdx.x] = ldf(att2, threadIdx.x, wide);
  }
  __syncthreads();
  int t = blockIdx.x * 256 + threadIdx.x;
  if (t >= N * HEADS) return;
  int n = t >> 2, hh = t & 3;
  const u16* p = h + (size_t)n * HID + hh * DH;
  float acc1 = 0.f, acc2 = 0.f;
#pragma unroll
  for (int d = 0; d < DH; ++d) {
    float f = us2f(p[d]);
    acc1 += f * s1[hh * DH + d];
    acc2 += f * s2[hh * DH + d];
  }
  a1[t] = fin(acc1);
  a2[t] = fin(acc2);
}

// ---- per-node logits: 4 att vectors, ONE h read (paper h) ------------------
__global__ __launch_bounds__(256) void compute_a4(
    const u16* __restrict__ h,
    const void* __restrict__ att1, const void* __restrict__ att2,
    const void* __restrict__ att3, const void* __restrict__ att4,
    float* __restrict__ a1, float* __restrict__ a2,
    float* __restrict__ a3, float* __restrict__ a4,
    int N, const int* __restrict__ flag_f)
{
  const int wide = *flag_f;
  __shared__ float s1[HID], s2[HID], s3[HID], s4[HID];
  if (threadIdx.x < HID) {
    s1[threadIdx.x] = ldf(att1, threadIdx.x, wide);
    s2[threadIdx.x] = ldf(att2, threadIdx.x, wide);
    s3[threadIdx.x] = ldf(att3, threadIdx.x, wide);
    s4[threadIdx.x] = ldf(att4, threadIdx.x, wide);
  }
  __syncthreads();
  int t = blockIdx.x * 256 + threadIdx.x;
  if (t >= N * HEADS) return;
  int n = t >> 2, hh = t & 3;
  const u16* p = h + (size_t)n * HID + hh * DH;
  float acc1 = 0.f, acc2 = 0.f, acc3 = 0.f, acc4 = 0.f;
#pragma unroll
  for (int d = 0; d < DH; ++d) {
    float f = us2f(p[d]);
    int c = hh * DH + d;
    acc1 += f * s1[c];
    acc2 += f * s2[c];
    acc3 += f * s3[c];
    acc4 += f * s4[c];
  }
  a1[t] = fin(acc1);
  a2[t] = fin(acc2);
  a3[t] = fin(acc3);
  a4[t] = fin(acc4);
}

// ---- CSR build (all 3 edge types in one pass) ------------------------------
__global__ __launch_bounds__(256) void hist3_kernel(
    const int* __restrict__ d0, int E0, int N0, int* __restrict__ g0,
    const int* __restrict__ d1, int E1, int N1, int* __restrict__ g1,
    const int* __restrict__ d2, int E2, int N2, int* __restrict__ g2,
    const int* __restrict__ flag_i)
{
  int e = blockIdx.x * 256 + threadIdx.x;
  int sh = *flag_i;
  if (e < E0) {
    atomicAdd(&g0[ld_idx(d0, e, sh, N0)], 1);
  } else if (e < E0 + E1) {
    atomicAdd(&g1[ld_idx(d1, e - E0, sh, N1)], 1);
  } else if (e < E0 + E1 + E2) {
    atomicAdd(&g2[ld_idx(d2, e - E0 - E1, sh, N2)], 1);
  }
}

__global__ __launch_bounds__(256) void scan1_kernel(
    const int* __restrict__ deg, int Nd, int* __restrict__ rowptr,
    int* __restrict__ blksum)
{
  __shared__ int ssum[256];
  int base = blockIdx.x * 1024;
  int t = threadIdx.x;
  int idx0 = base + t * 4;
  int v[4];
#pragma unroll
  for (int j = 0; j < 4; ++j) v[j] = (idx0 + j < Nd) ? deg[idx0 + j] : 0;
  int tsum = v[0] + v[1] + v[2] + v[3];
  ssum[t] = tsum;
  __syncthreads();
  for (int ofs = 1; ofs < 256; ofs <<= 1) {
    int x = (t >= ofs) ? ssum[t - ofs] : 0;
    __syncthreads();
    ssum[t] += x;
    __syncthreads();
  }
  if (t == 255) blksum[blockIdx.x] = ssum[255];
  int run = ssum[t] - tsum;
#pragma unroll
  for (int j = 0; j < 4; ++j) {
    if (idx0 + j < Nd) rowptr[idx0 + j] = run;
    run += v[j];
  }
}

// three independent tiny serial scans, one launch
__global__ void scan2x3_kernel(int* __restrict__ b0, int n0,
                               int* __restrict__ b1, int n1,
                               int* __restrict__ b2, int n2)
{
  if (blockIdx.x == 0) {
    if (threadIdx.x == 0) { int r = 0; for (int i = 0; i < n0; ++i) { int t = b0[i]; b0[i] = r; r += t; } }
    if (threadIdx.x == 1) { int r = 0; for (int i = 0; i < n1; ++i) { int t = b1[i]; b1[i] = r; r += t; } }
    if (threadIdx.x == 2) { int r = 0; for (int i = 0; i < n2; ++i) { int t = b2[i]; b2[i] = r; r += t; } }
  }
}

__global__ __launch_bounds__(256) void scan3_kernel(
    int* __restrict__ rowptr, int* __restrict__ cursor,
    const int* __restrict__ blksum, int Nd, int E)
{
  int i = blockIdx.x * 256 + threadIdx.x;
  if (i < Nd) {
    int v = rowptr[i] + blksum[i >> 10];
    rowptr[i] = v;
    cursor[i] = v;
  }
  if (i == 0) rowptr[Nd] = E;
}

__global__ __launch_bounds__(256) void reorder3_kernel(
    const int* __restrict__ s0, const int* __restrict__ d0, int E0, int Ns0, int N0,
    int* __restrict__ c0, int* __restrict__ o0,
    const int* __restrict__ s1, const int* __restrict__ d1, int E1, int Ns1, int N1,
    int* __restrict__ c1, int* __restrict__ o1,
    const int* __restrict__ s2, const int* __restrict__ d2, int E2, int Ns2, int N2,
    int* __restrict__ c2, int* __restrict__ o2,
    const int* __restrict__ flag_i)
{
  int e = blockIdx.x * 256 + threadIdx.x;
  int sh = *flag_i;
  if (e < E0) {
    int d = ld_idx(d0, e, sh, N0), s = ld_idx(s0, e, sh, Ns0);
    o0[atomicAdd(&c0[d], 1)] = s;
  } else if (e < E0 + E1) {
    int ee = e - E0;
    int d = ld_idx(d1, ee, sh, N1), s = ld_idx(s1, ee, sh, Ns1);
    o1[atomicAdd(&c1[d], 1)] = s;
  } else if (e < E0 + E1 + E2) {
    int ee = e - E0 - E1;
    int d = ld_idx(d2, ee, sh, N2), s = ld_idx(s2, ee, sh, Ns2);
    o2[atomicAdd(&c2[d], 1)] = s;
  }
}

// ---- gather edge conv: one wave per dst node, lane = 2 channels ------------
// SINGLE pass, branchless online softmax (running max + rescale).
__global__ __launch_bounds__(256) void gather_conv(
    const int* __restrict__ rowptr, const int* __restrict__ csr_src,
    const float* __restrict__ a_s, const float* __restrict__ a_d,
    const u16* __restrict__ h_src, u16* __restrict__ o,
    int lo, int rows)
{
  int wid = (blockIdx.x * 256 + threadIdx.x) >> 6;
  if (wid >= rows) return;
  int n = lo + wid;
  int lane = threadIdx.x & 63;
  int hh = lane >> 4;
  int start = rowptr[n], end = rowptr[n + 1];
  float ad = a_d[(size_t)n * HEADS + hh];
  float m = -1e30f, den = 0.f, n0 = 0.f, n1 = 0.f;
  int e = start;
  for (; e + 4 <= end; e += 4) {
    int s0 = csr_src[e],     s1 = csr_src[e + 1];
    int s2 = csr_src[e + 2], s3 = csr_src[e + 3];
    float x0 = a_s[(size_t)s0 * HEADS + hh] + ad;
    float x1 = a_s[(size_t)s1 * HEADS + hh] + ad;
    float x2 = a_s[(size_t)s2 * HEADS + hh] + ad;
    float x3 = a_s[(size_t)s3 * HEADS + hh] + ad;
    ushort2 h0 = *(const ushort2*)(h_src + (size_t)s0 * HID + 2 * lane);
    ushort2 h1 = *(const ushort2*)(h_src + (size_t)s1 * HID + 2 * lane);
    ushort2 h2 = *(const ushort2*)(h_src + (size_t)s2 * HID + 2 * lane);
    ushort2 h3 = *(const ushort2*)(h_src + (size_t)s3 * HID + 2 * lane);
    x0 = (x0 > 0.f) ? x0 : NEG * x0;
    x1 = (x1 > 0.f) ? x1 : NEG * x1;
    x2 = (x2 > 0.f) ? x2 : NEG * x2;
    x3 = (x3 > 0.f) ? x3 : NEG * x3;
    float mloc = fmaxf(fmaxf(x0, x1), fmaxf(x2, x3));
    float mn = fmaxf(m, mloc);
    float sc = __expf(m - mn);           // 0 on first batch, 1 if max unchanged
    float e0 = __expf(x0 - mn), e1 = __expf(x1 - mn);
    float e2 = __expf(x2 - mn), e3 = __expf(x3 - mn);
    den = den * sc + ((e0 + e1) + (e2 + e3));
    n0  = n0 * sc + (e0 * us2f(h0.x) + e1 * us2f(h1.x))
                  + (e2 * us2f(h2.x) + e3 * us2f(h3.x));
    n1  = n1 * sc + (e0 * us2f(h0.y) + e1 * us2f(h1.y))
                  + (e2 * us2f(h2.y) + e3 * us2f(h3.y));
    m = mn;
  }
  for (; e < end; ++e) {
    int s = csr_src[e];
    float x = a_s[(size_t)s * HEADS + hh] + ad;
    ushort2 hv = *(const ushort2*)(h_src + (size_t)s * HID + 2 * lane);
    x = (x > 0.f) ? x : NEG * x;
    float mn = fmaxf(m, x);
    float sc = __expf(m - mn);
    float ex = __expf(x - mn);
    den = den * sc + ex;
    n0  = n0 * sc + ex * us2f(hv.x);
    n1  = n1 * sc + ex * us2f(hv.y);
    m = mn;
  }
  float inv = 1.f / (den + 1e-16f);
  ushort2 st;
  st.x = f2us(fmaxf(n0 * inv, 0.f));
  st.y = f2us(fmaxf(n1 * inv, 0.f));
  *(ushort2*)(o + (size_t)wid * HID + 2 * lane) = st;
}

// ---- semantic softmax ------------------------------------------------------
__global__ void score_softmax(const float* __restrict__ S, const void* __restrict__ q,
                              float* __restrict__ attn, float invN,
                              const int* __restrict__ flag_f)
{
  if (threadIdx.x == 0 && blockIdx.x == 0) {
    const int wide = *flag_f;
    float s0 = 0.f, s1 = 0.f;
    for (int c = 0; c < HID; ++c) {
      float qc = ldf(q, c, wide);
      s0 += qc * S[c] * invN;
      s1 += qc * S[HID + c] * invN;
    }
    float m = fmaxf(s0, s1);
    float e0 = __expf(s0 - m), e1 = __expf(s1 - m);
    attn[0] = e0 / (e0 + e1);
    attn[1] = e1 / (e0 + e1);
  }
}

// ---- paper out: y = a0*Pw + a1*Pc + blin  (elem_off = NA*OUT_F) ------------
__global__ __launch_bounds__(256) void combine_paper(
    const u16* __restrict__ Pw, const u16* __restrict__ Pc,
    const float* __restrict__ attn, const void* __restrict__ blin,
    void* __restrict__ out, size_t elem_off, int N,
    const int* __restrict__ flag_f)
{
  int t = blockIdx.x * 256 + threadIdx.x;
  if (t >= N * 16) return;
  const int wide = *flag_f;
  int n = t >> 4, cq = t & 15;
  const float a0 = attn[0], a1 = attn[1];
  size_t i = (size_t)n * OUT_F + cq * 4;
  ushort4 w4 = *(const ushort4*)&Pw[i];
  ushort4 c4 = *(const ushort4*)&Pc[i];
  float v[4];
  v[0] = a0 * us2f(w4.x) + a1 * us2f(c4.x) + ldf(blin, cq * 4 + 0, wide);
  v[1] = a0 * us2f(w4.y) + a1 * us2f(c4.y) + ldf(blin, cq * 4 + 1, wide);
  v[2] = a0 * us2f(w4.z) + a1 * us2f(c4.z) + ldf(blin, cq * 4 + 2, wide);
  v[3] = a0 * us2f(w4.w) + a1 * us2f(c4.w) + ldf(blin, cq * 4 + 3, wide);
  size_t oi = elem_off + i;
  if (wide) {
    float4 ov = {v[0], v[1], v[2], v[3]};
    *(float4*)&((float*)out)[oi] = ov;
  } else {
    ushort4 ov;
    ov.x = f2us(v[0]); ov.y = f2us(v[1]); ov.z = f2us(v[2]); ov.w = f2us(v[3]);
    *(ushort4*)&((u16*)out)[oi] = ov;
  }
}

// ---------------------------------------------------------------------------
extern "C" void kernel_launch(void* const* d_in, const int* in_sizes, int n_in,
                              void* d_out, int out_size, void* d_ws, size_t ws_size,
                              hipStream_t stream)
{
  const int NA = in_sizes[0] / IN_F;   // 100000
  const int NP = in_sizes[1] / IN_F;   // 200000
  const int E_w = in_sizes[2], E_wb = in_sizes[4], E_c = in_sizes[6];

  const void* x_a   = d_in[0];
  const void* x_p   = d_in[1];
  const int* w_src  = (const int*)d_in[2];
  const int* w_dst  = (const int*)d_in[3];
  const int* wb_src = (const int*)d_in[4];
  const int* wb_dst = (const int*)d_in[5];
  const int* c_src  = (const int*)d_in[6];
  const int* c_dst  = (const int*)d_in[7];
  const void* W_pa  = d_in[8];
  const void* b_pa  = d_in[9];
  const void* W_pp  = d_in[10];
  const void* b_pp  = d_in[11];
  const void* at_s_w  = d_in[12];
  const void* at_d_w  = d_in[13];
  const void* at_s_wb = d_in[14];
  const void* at_d_wb = d_in[15];
  const void* at_s_c  = d_in[16];
  const void* at_d_c  = d_in[17];
  const void* W_k   = d_in[18];
  const void* b_k   = d_in[19];
  const void* q     = d_in[20];
  const void* W_lin = d_in[21];
  const void* b_lin = d_in[22];

  // ---- workspace layout ----
  char* ws = (char*)d_ws;
  size_t off = 0;
  auto alloc = [&](size_t bytes) -> void* {
    void* p = ws + off;
    off += (bytes + 255) & ~(size_t)255;
    return p;
  };
  int*   flag_f = (int*)alloc(4);
  int*   flag_i = (int*)alloc(4);
  float* attn   = (float*)alloc(8 * 4);
  float* S      = (float*)alloc(2 * HID * 4);
  u16*   h_a    = (u16*)alloc((size_t)NA * HID * 2);
  u16*   h_p    = (u16*)alloc((size_t)NP * HID * 2);
  float* aA_ws  = (float*)alloc((size_t)NA * HEADS * 4);
  float* aA_wbd = (float*)alloc((size_t)NA * HEADS * 4);
  float* aP_wd  = (float*)alloc((size_t)NP * HEADS * 4);
  float* aP_wbs = (float*)alloc((size_t)NP * HEADS * 4);
  float* aP_cs  = (float*)alloc((size_t)NP * HEADS * 4);
  float* aP_cd  = (float*)alloc((size_t)NP * HEADS * 4);
  u16*   Pw16   = (u16*)alloc((size_t)NP * OUT_F * 2);
  u16*   Pc16   = (u16*)alloc((size_t)NP * OUT_F * 2);
  // per-type CSR buffers (deg blocks contiguous for one memset)
  int*   deg3   = (int*)alloc(((size_t)NP + NA + NP) * 4);
  int*   degW   = deg3;
  int*   degWB  = deg3 + NP;
  int*   degC   = deg3 + NP + NA;
  int*   rpW    = (int*)alloc(((size_t)NP + 1) * 4);
  int*   rpWB   = (int*)alloc(((size_t)NA + 1) * 4);
  int*   rpC    = (int*)alloc(((size_t)NP + 1) * 4);
  int*   curW   = (int*)alloc((size_t)NP * 4);
  int*   curWB  = (int*)alloc((size_t)NA * 4);
  int*   curC   = (int*)alloc((size_t)NP * 4);
  int*   bsW    = (int*)alloc(1024);
  int*   bsWB   = (int*)alloc(1024);
  int*   bsC    = (int*)alloc(1024);
  int*   csW    = (int*)alloc((size_t)E_w * 4);
  int*   csWB   = (int*)alloc((size_t)E_wb * 4);
  int*   csC    = (int*)alloc((size_t)E_c * 4);
  u16*   o16    = (u16*)(ws + off);             // rest of ws, chunked, bf16
  size_t o_bytes = (ws_size > off) ? (ws_size - off) : 0;
  long long cap = (long long)(o_bytes / ((size_t)HID * 2));
  int rc = (int)(cap > NP ? NP : cap);
  rc &= ~63;
  if (rc < 64) rc = 64;

  // ---- detection ----
  detect_float_width<<<1, 256, 0, stream>>>((const u16*)x_a, 4096, flag_f);
  detect_idx_width<<<1, 256, 0, stream>>>(w_src, 512, flag_i);

  // ---- projections + logits ----
  {
    int gA = (NA / 16 + 3) / 4; if (gA > 2048) gA = 2048;
    int gP = (NP / 16 + 3) / 4; if (gP > 2048) gP = 2048;
    proj_mfma<<<gA, 256, 0, stream>>>(x_a, W_pa, b_pa, h_a, NA, flag_f);
    proj_mfma<<<gP, 256, 0, stream>>>(x_p, W_pp, b_pp, h_p, NP, flag_f);
  }
  compute_a2<<<(NA * HEADS + 255) / 256, 256, 0, stream>>>(h_a, at_s_w, at_d_wb, aA_ws, aA_wbd, NA, flag_f);
  compute_a4<<<(NP * HEADS + 255) / 256, 256, 0, stream>>>(
      h_p, at_d_w, at_s_wb, at_s_c, at_d_c, aP_wd, aP_wbs, aP_cs, aP_cd, NP, flag_f);

  hipMemsetAsync(S, 0, 2 * HID * 4, stream);

  // ---- merged CSR build (all 3 edge types) ----
  hipMemsetAsync(deg3, 0, ((size_t)NP + NA + NP) * 4, stream);
  {
    long long Etot = (long long)E_w + E_wb + E_c;
    hist3_kernel<<<(Etot + 255) / 256, 256, 0, stream>>>(
        w_dst, E_w, NP, degW, wb_dst, E_wb, NA, degWB, c_dst, E_c, NP, degC, flag_i);
    int nbW = (NP + 1023) / 1024, nbWB = (NA + 1023) / 1024, nbC = (NP + 1023) / 1024;
    scan1_kernel<<<nbW, 256, 0, stream>>>(degW, NP, rpW, bsW);
    scan1_kernel<<<nbWB, 256, 0, stream>>>(degWB, NA, rpWB, bsWB);
    scan1_kernel<<<nbC, 256, 0, stream>>>(degC, NP, rpC, bsC);
    scan2x3_kernel<<<1, 64, 0, stream>>>(bsW, nbW, bsWB, nbWB, bsC, nbC);
    scan3_kernel<<<(NP + 255) / 256, 256, 0, stream>>>(rpW, curW, bsW, NP, E_w);
    scan3_kernel<<<(NA + 255) / 256, 256, 0, stream>>>(rpWB, curWB, bsWB, NA, E_wb);
    scan3_kernel<<<(NP + 255) / 256, 256, 0, stream>>>(rpC, curC, bsC, NP, E_c);
    reorder3_kernel<<<(Etot + 255) / 256, 256, 0, stream>>>(
        w_src, w_dst, E_w, NA, NP, curW, csW,
        wb_src, wb_dst, E_wb, NP, NA, curWB, csWB,
        c_src, c_dst, E_c, NP, NP, curC, csC, flag_i);
  }

  // ---- writtenby: paper -> author (direct author output) ----
  for (int lo = 0; lo < NA; lo += rc) {
    int rows = (NA - lo < rc) ? (NA - lo) : rc;
    gather_conv<<<(rows + 3) / 4, 256, 0, stream>>>(rpWB, csWB, aP_wbs, aA_wbd, h_p, o16, lo, rows);
    int g = (rows / 16 + 3) / 4; if (g > 2048) g = 2048; if (g < 1) g = 1;
    author_mfma<<<g, 256, 0, stream>>>(o16, rows, lo, W_lin, b_lin, d_out, flag_f);
  }

  // ---- writes: author -> paper (S0 colsum + Pw) ----
  for (int lo = 0; lo < NP; lo += rc) {
    int rows = (NP - lo < rc) ? (NP - lo) : rc;
    gather_conv<<<(rows + 3) / 4, 256, 0, stream>>>(rpW, csW, aA_ws, aP_wd, h_a, o16, lo, rows);
    int g = (rows / 16 + 3) / 4; if (g > 2048) g = 2048; if (g < 1) g = 1;
    colsum_mfma<<<g, 256, 0, stream>>>(o16, rows, W_k, b_k, S, flag_f);
    linW_mfma<<<g, 256, 0, stream>>>(o16, rows, W_lin, Pw16 + (size_t)lo * OUT_F, flag_f);
  }

  // ---- cites: paper -> paper (S1 colsum + Pc) ----
  for (int lo = 0; lo < NP; lo += rc) {
    int rows = (NP - lo < rc) ? (NP - lo) : rc;
    gather_conv<<<(rows + 3) / 4, 256, 0, stream>>>(rpC, csC, aP_cs, aP_cd, h_p, o16, lo, rows);
    int g = (rows / 16 + 3) / 4; if (g > 2048) g = 2048; if (g < 1) g = 1;
    colsum_mfma<<<g, 256, 0, stream>>>(o16, rows, W_k, b_k, S + HID, flag_f);
    linW_mfma<<<g, 256, 0, stream>>>(o16, rows, W_lin, Pc16 + (size_t)lo * OUT_F, flag_f);
  }

  // ---- semantic softmax + paper output ----
  score_softmax<<<1, 64, 0, stream>>>(S, q, attn, 1.0f / (float)NP, flag_f);
  combine_paper<<<((size_t)NP * 16 + 255) / 256, 256, 0, stream>>>(Pw16, Pc16, attn, b_lin, d_out, (size_t)NA * OUT_F, NP, flag_f);
}

// Round 8
// 1188.068 us; speedup vs baseline: 1.1925x; 1.1925x over previous
//
#include <hip/hip_runtime.h>
#include <hip/hip_bf16.h>

// HANConv (HANModel). R8: revert MFMA kernels to the measured-1287 (R6)
// bodies (R7 strip restructure implicated in +130 regression). Keep
// compute_a4 (h_p read once for 4 logit sets). NEW: XCD-partitioned
// reorder — 8 block-groups each scan all edges, write only their dst
// partition (p = d*8/Nd == blockIdx&7). With round-robin block->XCD
// mapping each csr line is dirty in ONE XCD's L2, killing the 17x
// write-allocate amplification measured in R7 (212MB HBM writes for
// 12MB payload). Correct regardless of actual mapping.

#define HEADS 4
#define DH 32
#define HID 128
#define IN_F 128
#define OUT_F 64
#define NEG 0.2f

typedef unsigned short u16;
typedef unsigned int u32;
typedef __attribute__((ext_vector_type(8))) short short8;
typedef __attribute__((ext_vector_type(4))) float f32x4;

__device__ __forceinline__ float us2f(u16 u){ return __uint_as_float(((u32)u) << 16); }
__device__ __forceinline__ u16 f2us(float f){            // f32 -> bf16 RNE
  u32 u = __float_as_uint(f);
  u += 0x7fffu + ((u >> 16) & 1u);
  return (u16)(u >> 16);
}
__device__ __forceinline__ float fin(float v){ return (fabsf(v) < 1e30f) ? v : 0.f; }
__device__ __forceinline__ u16 san16(u16 r){ return (((r >> 7) & 0xff) == 0xff) ? (u16)0 : r; }
// fast tanh via exp2-backed __expf; clamp keeps (t-1)/(t+1) finite.
__device__ __forceinline__ float ftanh(float x){
  float t = __expf(fminf(fmaxf(2.f * x, -30.f), 30.f));
  return __fdividef(t - 1.f, t + 1.f);
}
// width-adaptive sanitized loads from raw input tensors
__device__ __forceinline__ float ldf(const void* p, size_t i, int wide){
  float v = wide ? ((const float*)p)[i] : us2f(((const u16*)p)[i]);
  return fin(v);
}
__device__ __forceinline__ u16 ld16(const void* p, size_t i, int wide){
  if (wide) return f2us(fin(((const float*)p)[i]));
  return san16(((const u16*)p)[i]);
}
__device__ __forceinline__ int ld_idx(const int* __restrict__ p, int e, int sh, int n){
  int v = p[(size_t)e << sh];
  return v < 0 ? 0 : (v >= n ? n - 1 : v);
}

// ---- detection kernels -----------------------------------------------------
__global__ void detect_float_width(const u16* __restrict__ x, int n, int* __restrict__ flag)
{
  __shared__ int cnt;
  if (threadIdx.x == 0) cnt = 0;
  __syncthreads();
  int local = 0;
  for (int i = threadIdx.x; i < n; i += blockDim.x) {
    int e = (x[i] >> 7) & 0xff;
    if (e == 0 || (e >= 100 && e <= 150)) local++;
  }
  atomicAdd(&cnt, local);
  __syncthreads();
  if (threadIdx.x == 0) *flag = (cnt < (n * 9) / 10) ? 1 : 0;  // 1 = f32
}
__global__ void detect_idx_width(const int* __restrict__ s, int n, int* __restrict__ flag)
{
  __shared__ int any;
  if (threadIdx.x == 0) any = 0;
  __syncthreads();
  for (int i = threadIdx.x; i < n; i += blockDim.x)
    if (s[2 * i + 1] != 0) atomicOr(&any, 1);
  __syncthreads();
  if (threadIdx.x == 0) *flag = any ? 0 : 1;                   // 1 = int64
}

// ---- MFMA GEMM infrastructure ---------------------------------------------
// B staged transposed in LDS: Bt[c][k] bf16, row stride 256B, XOR-swizzle
// byte ^= (c&7)<<4 so 16-lane column-slice ds_read_b128 is ~conflict-free.
template<int NC>
__device__ __forceinline__ void stage_B1(const void* W1, int wide, u16* Bt)
{
  for (int i = threadIdx.x; i < 128 * NC; i += 256) {
    int k = i / NC, c = i - k * NC;
    u16 v = ld16(W1, (size_t)k * NC + c, wide);
    u32 boff = ((u32)c << 8) + (((u32)(k << 1)) ^ (((u32)(c & 7)) << 4));
    *(u16*)((char*)Bt + boff) = v;
  }
}

// B fragment for tile t, k-step kk: lane c=(t*16+(l&15)), 8 bf16 k-contiguous
__device__ __forceinline__ short8 ldsB(const u16* Bt, int t, int lane, int kk)
{
  const int c = (t << 4) + (lane & 15);
  const u32 boff = ((u32)c << 8) +
      (((u32)(((lane >> 4) << 4) + (kk << 6))) ^ (((u32)(c & 7)) << 4));
  return *(const short8*)((const char*)Bt + boff);
}

// A fragment from raw input x (runtime f32/bf16), row rb, 8 k-contiguous bf16
__device__ __forceinline__ short8 ldA_x(const void* x, size_t rb, int kg, int kk, int wide)
{
  short8 v;
  const size_t base = rb + (size_t)(kg * 8 + kk * 32);
  if (wide) {
    const float* p = (const float*)x + base;
    const float4 f0 = *(const float4*)p;
    const float4 f1 = *(const float4*)(p + 4);
    v[0] = (short)f2us(fin(f0.x)); v[1] = (short)f2us(fin(f0.y));
    v[2] = (short)f2us(fin(f0.z)); v[3] = (short)f2us(fin(f0.w));
    v[4] = (short)f2us(fin(f1.x)); v[5] = (short)f2us(fin(f1.y));
    v[6] = (short)f2us(fin(f1.z)); v[7] = (short)f2us(fin(f1.w));
  } else {
    const short8 raw = *(const short8*)((const u16*)x + base);
#pragma unroll
    for (int j = 0; j < 8; ++j) v[j] = (short)san16((u16)raw[j]);
  }
  return v;
}

// A fragment from our clean bf16 o buffer
__device__ __forceinline__ short8 ldA_o(const u16* o, size_t rb, int kg, int kk)
{
  return *(const short8*)(o + rb + (size_t)(kg * 8 + kk * 32));
}

// ---- projection: h[n,c] = bf16(x[n,:] @ W[:,c] + b[c]) ---------------------
__global__ __launch_bounds__(256, 2) void proj_mfma(
    const void* __restrict__ x, const void* __restrict__ W,
    const void* __restrict__ b, u16* __restrict__ h, int N,
    const int* __restrict__ flag_f)
{
  const int wide = *flag_f;
  __shared__ u16 Bt[128 * 128];   // 32 KB
  stage_B1<HID>(W, wide, Bt);
  __syncthreads();
  const int w = threadIdx.x >> 6, lane = threadIdx.x & 63;
  const int r16 = lane & 15, kg = lane >> 4;
  float bv[8];
#pragma unroll
  for (int t = 0; t < 8; ++t) bv[t] = ldf(b, (t << 4) + r16, wide);
  const int nstrips = (N + 63) >> 6;
  for (int sidx = blockIdx.x; sidx < nstrips; sidx += gridDim.x) {
    const int rowbase = (sidx << 6) + (w << 4);
    int arow = rowbase + r16;
    if (arow >= N) arow = N - 1;
    const size_t rb = (size_t)arow * IN_F;
    f32x4 acc[8];
#pragma unroll
    for (int t = 0; t < 8; ++t) acc[t] = (f32x4){0.f, 0.f, 0.f, 0.f};
#pragma unroll
    for (int kk = 0; kk < 4; ++kk) {
      const short8 a = ldA_x(x, rb, kg, kk, wide);
#pragma unroll
      for (int t = 0; t < 8; ++t)
        acc[t] = __builtin_amdgcn_mfma_f32_16x16x32_bf16(a, ldsB(Bt, t, lane, kk), acc[t], 0, 0, 0);
    }
#pragma unroll
    for (int t = 0; t < 8; ++t) {
      const int col = (t << 4) + r16;
#pragma unroll
      for (int j = 0; j < 4; ++j) {
        const int row = rowbase + (kg << 2) + j;
        if (row < N) h[(size_t)row * HID + col] = f2us(acc[t][j] + bv[t]);
      }
    }
  }
}

// ---- colsum: S[c] += sum_n ftanh(o(relu'd bf16) @ Wk + bk) -----------------
__global__ __launch_bounds__(256, 2) void colsum_mfma(
    const u16* __restrict__ o, int rows, const void* __restrict__ Wk,
    const void* __restrict__ bk, float* __restrict__ S,
    const int* __restrict__ flag_f)
{
  const int wide = *flag_f;
  __shared__ u16 Bt[128 * 128];   // 32 KB
  __shared__ float sred[4][HID];  // 2 KB
  stage_B1<HID>(Wk, wide, Bt);
  __syncthreads();
  const int w = threadIdx.x >> 6, lane = threadIdx.x & 63;
  const int r16 = lane & 15, kg = lane >> 4;
  float bkv[8];
#pragma unroll
  for (int t = 0; t < 8; ++t) bkv[t] = ldf(bk, (t << 4) + r16, wide);
  float scs[8] = {0.f, 0.f, 0.f, 0.f, 0.f, 0.f, 0.f, 0.f};
  const int nstrips = (rows + 63) >> 6;
  for (int sidx = blockIdx.x; sidx < nstrips; sidx += gridDim.x) {
    const int rowbase = (sidx << 6) + (w << 4);
    int arow = rowbase + r16;
    if (arow >= rows) arow = rows - 1;
    const size_t rb = (size_t)arow * HID;
    f32x4 acc[8];
#pragma unroll
    for (int t = 0; t < 8; ++t) acc[t] = (f32x4){0.f, 0.f, 0.f, 0.f};
#pragma unroll
    for (int kk = 0; kk < 4; ++kk) {
      const short8 a = ldA_o(o, rb, kg, kk);
#pragma unroll
      for (int t = 0; t < 8; ++t)
        acc[t] = __builtin_amdgcn_mfma_f32_16x16x32_bf16(a, ldsB(Bt, t, lane, kk), acc[t], 0, 0, 0);
    }
#pragma unroll
    for (int t = 0; t < 8; ++t) {
#pragma unroll
      for (int j = 0; j < 4; ++j) {
        const int row = rowbase + (kg << 2) + j;
        if (row < rows) scs[t] += ftanh(acc[t][j] + bkv[t]);
      }
    }
  }
  // reduce: kg-groups share a column -> shfl over kg -> per-wave row -> atomic
#pragma unroll
  for (int t = 0; t < 8; ++t) {
    float v = scs[t];
    v += __shfl_xor(v, 16);
    v += __shfl_xor(v, 32);
    if (kg == 0) sred[w][(t << 4) + r16] = v;
  }
  __syncthreads();
  if (threadIdx.x < HID) {
    float v = sred[0][threadIdx.x] + sred[1][threadIdx.x] +
              sred[2][threadIdx.x] + sred[3][threadIdx.x];
    atomicAdd(&S[threadIdx.x], v);
  }
}

// ---- P = o(relu'd bf16) @ Wlin  (no bias) -> bf16 --------------------------
__global__ __launch_bounds__(256, 2) void linW_mfma(
    const u16* __restrict__ o, int rows, const void* __restrict__ Wlin,
    u16* __restrict__ P, const int* __restrict__ flag_f)
{
  const int wide = *flag_f;
  __shared__ u16 Bt[64 * 128];    // 16 KB
  stage_B1<OUT_F>(Wlin, wide, Bt);
  __syncthreads();
  const int w = threadIdx.x >> 6, lane = threadIdx.x & 63;
  const int r16 = lane & 15, kg = lane >> 4;
  const int nstrips = (rows + 63) >> 6;
  for (int sidx = blockIdx.x; sidx < nstrips; sidx += gridDim.x) {
    const int rowbase = (sidx << 6) + (w << 4);
    int arow = rowbase + r16;
    if (arow >= rows) arow = rows - 1;
    const size_t rb = (size_t)arow * HID;
    f32x4 acc[4];
#pragma unroll
    for (int t = 0; t < 4; ++t) acc[t] = (f32x4){0.f, 0.f, 0.f, 0.f};
#pragma unroll
    for (int kk = 0; kk < 4; ++kk) {
      const short8 a = ldA_o(o, rb, kg, kk);
#pragma unroll
      for (int t = 0; t < 4; ++t)
        acc[t] = __builtin_amdgcn_mfma_f32_16x16x32_bf16(a, ldsB(Bt, t, lane, kk), acc[t], 0, 0, 0);
    }
#pragma unroll
    for (int t = 0; t < 4; ++t) {
      const int col = (t << 4) + r16;
#pragma unroll
      for (int j = 0; j < 4; ++j) {
        const int row = rowbase + (kg << 2) + j;
        if (row < rows) P[(size_t)row * OUT_F + col] = f2us(acc[t][j]);
      }
    }
  }
}

// ---- author out: y = o(bf16,relu'd) @ Wlin + blin  (width-adaptive) --------
__global__ __launch_bounds__(256, 2) void author_mfma(
    const u16* __restrict__ o, int rows, int node0,
    const void* __restrict__ Wlin, const void* __restrict__ blin,
    void* __restrict__ out, const int* __restrict__ flag_f)
{
  const int wide = *flag_f;
  __shared__ u16 Bt[64 * 128];    // 16 KB
  stage_B1<OUT_F>(Wlin, wide, Bt);
  __syncthreads();
  const int w = threadIdx.x >> 6, lane = threadIdx.x & 63;
  const int r16 = lane & 15, kg = lane >> 4;
  float bv[4];
#pragma unroll
  for (int t = 0; t < 4; ++t) bv[t] = ldf(blin, (t << 4) + r16, wide);
  const int nstrips = (rows + 63) >> 6;
  for (int sidx = blockIdx.x; sidx < nstrips; sidx += gridDim.x) {
    const int rowbase = (sidx << 6) + (w << 4);
    int arow = rowbase + r16;
    if (arow >= rows) arow = rows - 1;
    const size_t rb = (size_t)arow * HID;
    f32x4 acc[4];
#pragma unroll
    for (int t = 0; t < 4; ++t) acc[t] = (f32x4){0.f, 0.f, 0.f, 0.f};
#pragma unroll
    for (int kk = 0; kk < 4; ++kk) {
      const short8 a = ldA_o(o, rb, kg, kk);
#pragma unroll
      for (int t = 0; t < 4; ++t)
        acc[t] = __builtin_amdgcn_mfma_f32_16x16x32_bf16(a, ldsB(Bt, t, lane, kk), acc[t], 0, 0, 0);
    }
#pragma unroll
    for (int t = 0; t < 4; ++t) {
      const int col = (t << 4) + r16;
#pragma unroll
      for (int j = 0; j < 4; ++j) {
        const int row = rowbase + (kg << 2) + j;
        if (row < rows) {
          const float val = acc[t][j] + bv[t];
          const size_t oi = (size_t)(node0 + row) * OUT_F + col;
          if (wide) ((float*)out)[oi] = val;
          else      ((u16*)out)[oi] = f2us(val);
        }
      }
    }
  }
}

// ---- per-node logits: 2 att vectors (author h) -----------------------------
__global__ __launch_bounds__(256) void compute_a2(
    const u16* __restrict__ h, const void* __restrict__ att1,
    const void* __restrict__ att2, float* __restrict__ a1,
    float* __restrict__ a2, int N, const int* __restrict__ flag_f)
{
  const int wide = *flag_f;
  __shared__ float s1[HID], s2[HID];
  if (threadIdx.x < HID) {
    s1[threadIdx.x] = ldf(att1, threadIdx.x, wide);
    s2[threadIdx.x] = ldf(att2, threadIdx.x, wide);
  }
  __syncthreads();
  int t = blockIdx.x * 256 + threadIdx.x;
  if (t >= N * HEADS) return;
  int n = t >> 2, hh = t & 3;
  const u16* p = h + (size_t)n * HID + hh * DH;
  float acc1 = 0.f, acc2 = 0.f;
#pragma unroll
  for (int d = 0; d < DH; ++d) {
    float f = us2f(p[d]);
    acc1 += f * s1[hh * DH + d];
    acc2 += f * s2[hh * DH + d];
  }
  a1[t] = fin(acc1);
  a2[t] = fin(acc2);
}

// ---- per-node logits: 4 att vectors, ONE h read (paper h) ------------------
__global__ __launch_bounds__(256) void compute_a4(
    const u16* __restrict__ h,
    const void* __restrict__ att1, const void* __restrict__ att2,
    const void* __restrict__ att3, const void* __restrict__ att4,
    float* __restrict__ a1, float* __restrict__ a2,
    float* __restrict__ a3, float* __restrict__ a4,
    int N, const int* __restrict__ flag_f)
{
  const int wide = *flag_f;
  __shared__ float s1[HID], s2[HID], s3[HID], s4[HID];
  if (threadIdx.x < HID) {
    s1[threadIdx.x] = ldf(att1, threadIdx.x, wide);
    s2[threadIdx.x] = ldf(att2, threadIdx.x, wide);
    s3[threadIdx.x] = ldf(att3, threadIdx.x, wide);
    s4[threadIdx.x] = ldf(att4, threadIdx.x, wide);
  }
  __syncthreads();
  int t = blockIdx.x * 256 + threadIdx.x;
  if (t >= N * HEADS) return;
  int n = t >> 2, hh = t & 3;
  const u16* p = h + (size_t)n * HID + hh * DH;
  float acc1 = 0.f, acc2 = 0.f, acc3 = 0.f, acc4 = 0.f;
#pragma unroll
  for (int d = 0; d < DH; ++d) {
    float f = us2f(p[d]);
    int c = hh * DH + d;
    acc1 += f * s1[c];
    acc2 += f * s2[c];
    acc3 += f * s3[c];
    acc4 += f * s4[c];
  }
  a1[t] = fin(acc1);
  a2[t] = fin(acc2);
  a3[t] = fin(acc3);
  a4[t] = fin(acc4);
}

// ---- CSR build -------------------------------------------------------------
__global__ __launch_bounds__(256) void hist3_kernel(
    const int* __restrict__ d0, int E0, int N0, int* __restrict__ g0,
    const int* __restrict__ d1, int E1, int N1, int* __restrict__ g1,
    const int* __restrict__ d2, int E2, int N2, int* __restrict__ g2,
    const int* __restrict__ flag_i)
{
  int e = blockIdx.x * 256 + threadIdx.x;
  int sh = *flag_i;
  if (e < E0) {
    atomicAdd(&g0[ld_idx(d0, e, sh, N0)], 1);
  } else if (e < E0 + E1) {
    atomicAdd(&g1[ld_idx(d1, e - E0, sh, N1)], 1);
  } else if (e < E0 + E1 + E2) {
    atomicAdd(&g2[ld_idx(d2, e - E0 - E1, sh, N2)], 1);
  }
}

__global__ __launch_bounds__(256) void scan1_kernel(
    const int* __restrict__ deg, int Nd, int* __restrict__ rowptr,
    int* __restrict__ blksum)
{
  __shared__ int ssum[256];
  int base = blockIdx.x * 1024;
  int t = threadIdx.x;
  int idx0 = base + t * 4;
  int v[4];
#pragma unroll
  for (int j = 0; j < 4; ++j) v[j] = (idx0 + j < Nd) ? deg[idx0 + j] : 0;
  int tsum = v[0] + v[1] + v[2] + v[3];
  ssum[t] = tsum;
  __syncthreads();
  for (int ofs = 1; ofs < 256; ofs <<= 1) {
    int x = (t >= ofs) ? ssum[t - ofs] : 0;
    __syncthreads();
    ssum[t] += x;
    __syncthreads();
  }
  if (t == 255) blksum[blockIdx.x] = ssum[255];
  int run = ssum[t] - tsum;
#pragma unroll
  for (int j = 0; j < 4; ++j) {
    if (idx0 + j < Nd) rowptr[idx0 + j] = run;
    run += v[j];
  }
}

// three independent tiny serial scans, one launch
__global__ void scan2x3_kernel(int* __restrict__ b0, int n0,
                               int* __restrict__ b1, int n1,
                               int* __restrict__ b2, int n2)
{
  if (blockIdx.x == 0) {
    if (threadIdx.x == 0) { int r = 0; for (int i = 0; i < n0; ++i) { int t = b0[i]; b0[i] = r; r += t; } }
    if (threadIdx.x == 1) { int r = 0; for (int i = 0; i < n1; ++i) { int t = b1[i]; b1[i] = r; r += t; } }
    if (threadIdx.x == 2) { int r = 0; for (int i = 0; i < n2; ++i) { int t = b2[i]; b2[i] = r; r += t; } }
  }
}

__global__ __launch_bounds__(256) void scan3_kernel(
    int* __restrict__ rowptr, int* __restrict__ cursor,
    const int* __restrict__ blksum, int Nd, int E)
{
  int i = blockIdx.x * 256 + threadIdx.x;
  if (i < Nd) {
    int v = rowptr[i] + blksum[i >> 10];
    rowptr[i] = v;
    cursor[i] = v;
  }
  if (i == 0) rowptr[Nd] = E;
}

// XCD-partitioned reorder: 8 block-groups (part = blockIdx&7) each scan the
// full edge list, writing only edges with dst in their partition. With the
// HW's round-robin block->XCD mapping, each csr/cursor line is owned by one
// XCD's L2 -> no cross-XCD write-allocate amplification. Exact integer
// partition test => every edge written exactly once under ANY mapping.
__global__ __launch_bounds__(256) void reorder_part(
    const int* __restrict__ src, const int* __restrict__ dst, int E,
    const int* __restrict__ flag_i, int Ns, int Nd,
    int* __restrict__ cursor, int* __restrict__ csr_src)
{
  const int part = blockIdx.x & 7;
  const int grp  = blockIdx.x >> 3;
  const int ngrp = gridDim.x >> 3;
  const int sh = *flag_i;
  for (int e = grp * 256 + threadIdx.x; e < E; e += ngrp * 256) {
    int d = ld_idx(dst, e, sh, Nd);
    if ((d * 8) / Nd == part) {          // d*8 < 2^24, exact
      int s = ld_idx(src, e, sh, Ns);
      csr_src[atomicAdd(&cursor[d], 1)] = s;
    }
  }
}

// ---- gather edge conv: one wave per dst node, lane = 2 channels ------------
// SINGLE pass, branchless online softmax (running max + rescale).
__global__ __launch_bounds__(256) void gather_conv(
    const int* __restrict__ rowptr, const int* __restrict__ csr_src,
    const float* __restrict__ a_s, const float* __restrict__ a_d,
    const u16* __restrict__ h_src, u16* __restrict__ o,
    int lo, int rows)
{
  int wid = (blockIdx.x * 256 + threadIdx.x) >> 6;
  if (wid >= rows) return;
  int n = lo + wid;
  int lane = threadIdx.x & 63;
  int hh = lane >> 4;
  int start = rowptr[n], end = rowptr[n + 1];
  float ad = a_d[(size_t)n * HEADS + hh];
  float m = -1e30f, den = 0.f, n0 = 0.f, n1 = 0.f;
  int e = start;
  for (; e + 4 <= end; e += 4) {
    int s0 = csr_src[e],     s1 = csr_src[e + 1];
    int s2 = csr_src[e + 2], s3 = csr_src[e + 3];
    float x0 = a_s[(size_t)s0 * HEADS + hh] + ad;
    float x1 = a_s[(size_t)s1 * HEADS + hh] + ad;
    float x2 = a_s[(size_t)s2 * HEADS + hh] + ad;
    float x3 = a_s[(size_t)s3 * HEADS + hh] + ad;
    ushort2 h0 = *(const ushort2*)(h_src + (size_t)s0 * HID + 2 * lane);
    ushort2 h1 = *(const ushort2*)(h_src + (size_t)s1 * HID + 2 * lane);
    ushort2 h2 = *(const ushort2*)(h_src + (size_t)s2 * HID + 2 * lane);
    ushort2 h3 = *(const ushort2*)(h_src + (size_t)s3 * HID + 2 * lane);
    x0 = (x0 > 0.f) ? x0 : NEG * x0;
    x1 = (x1 > 0.f) ? x1 : NEG * x1;
    x2 = (x2 > 0.f) ? x2 : NEG * x2;
    x3 = (x3 > 0.f) ? x3 : NEG * x3;
    float mloc = fmaxf(fmaxf(x0, x1), fmaxf(x2, x3));
    float mn = fmaxf(m, mloc);
    float sc = __expf(m - mn);           // 0 on first batch, 1 if max unchanged
    float e0 = __expf(x0 - mn), e1 = __expf(x1 - mn);
    float e2 = __expf(x2 - mn), e3 = __expf(x3 - mn);
    den = den * sc + ((e0 + e1) + (e2 + e3));
    n0  = n0 * sc + (e0 * us2f(h0.x) + e1 * us2f(h1.x))
                  + (e2 * us2f(h2.x) + e3 * us2f(h3.x));
    n1  = n1 * sc + (e0 * us2f(h0.y) + e1 * us2f(h1.y))
                  + (e2 * us2f(h2.y) + e3 * us2f(h3.y));
    m = mn;
  }
  for (; e < end; ++e) {
    int s = csr_src[e];
    float x = a_s[(size_t)s * HEADS + hh] + ad;
    ushort2 hv = *(const ushort2*)(h_src + (size_t)s * HID + 2 * lane);
    x = (x > 0.f) ? x : NEG * x;
    float mn = fmaxf(m, x);
    float sc = __expf(m - mn);
    float ex = __expf(x - mn);
    den = den * sc + ex;
    n0  = n0 * sc + ex * us2f(hv.x);
    n1  = n1 * sc + ex * us2f(hv.y);
    m = mn;
  }
  float inv = 1.f / (den + 1e-16f);
  ushort2 st;
  st.x = f2us(fmaxf(n0 * inv, 0.f));
  st.y = f2us(fmaxf(n1 * inv, 0.f));
  *(ushort2*)(o + (size_t)wid * HID + 2 * lane) = st;
}

// ---- semantic softmax ------------------------------------------------------
__global__ void score_softmax(const float* __restrict__ S, const void* __restrict__ q,
                              float* __restrict__ attn, float invN,
                              const int* __restrict__ flag_f)
{
  if (threadIdx.x == 0 && blockIdx.x == 0) {
    const int wide = *flag_f;
    float s0 = 0.f, s1 = 0.f;
    for (int c = 0; c < HID; ++c) {
      float qc = ldf(q, c, wide);
      s0 += qc * S[c] * invN;
      s1 += qc * S[HID + c] * invN;
    }
    float m = fmaxf(s0, s1);
    float e0 = __expf(s0 - m), e1 = __expf(s1 - m);
    attn[0] = e0 / (e0 + e1);
    attn[1] = e1 / (e0 + e1);
  }
}

// ---- paper out: y = a0*Pw + a1*Pc + blin  (elem_off = NA*OUT_F) ------------
__global__ __launch_bounds__(256) void combine_paper(
    const u16* __restrict__ Pw, const u16* __restrict__ Pc,
    const float* __restrict__ attn, const void* __restrict__ blin,
    void* __restrict__ out, size_t elem_off, int N,
    const int* __restrict__ flag_f)
{
  int t = blockIdx.x * 256 + threadIdx.x;
  if (t >= N * 16) return;
  const int wide = *flag_f;
  int n = t >> 4, cq = t & 15;
  const float a0 = attn[0], a1 = attn[1];
  size_t i = (size_t)n * OUT_F + cq * 4;
  ushort4 w4 = *(const ushort4*)&Pw[i];
  ushort4 c4 = *(const ushort4*)&Pc[i];
  float v[4];
  v[0] = a0 * us2f(w4.x) + a1 * us2f(c4.x) + ldf(blin, cq * 4 + 0, wide);
  v[1] = a0 * us2f(w4.y) + a1 * us2f(c4.y) + ldf(blin, cq * 4 + 1, wide);
  v[2] = a0 * us2f(w4.z) + a1 * us2f(c4.z) + ldf(blin, cq * 4 + 2, wide);
  v[3] = a0 * us2f(w4.w) + a1 * us2f(c4.w) + ldf(blin, cq * 4 + 3, wide);
  size_t oi = elem_off + i;
  if (wide) {
    float4 ov = {v[0], v[1], v[2], v[3]};
    *(float4*)&((float*)out)[oi] = ov;
  } else {
    ushort4 ov;
    ov.x = f2us(v[0]); ov.y = f2us(v[1]); ov.z = f2us(v[2]); ov.w = f2us(v[3]);
    *(ushort4*)&((u16*)out)[oi] = ov;
  }
}

// ---------------------------------------------------------------------------
extern "C" void kernel_launch(void* const* d_in, const int* in_sizes, int n_in,
                              void* d_out, int out_size, void* d_ws, size_t ws_size,
                              hipStream_t stream)
{
  const int NA = in_sizes[0] / IN_F;   // 100000
  const int NP = in_sizes[1] / IN_F;   // 200000
  const int E_w = in_sizes[2], E_wb = in_sizes[4], E_c = in_sizes[6];

  const void* x_a   = d_in[0];
  const void* x_p   = d_in[1];
  const int* w_src  = (const int*)d_in[2];
  const int* w_dst  = (const int*)d_in[3];
  const int* wb_src = (const int*)d_in[4];
  const int* wb_dst = (const int*)d_in[5];
  const int* c_src  = (const int*)d_in[6];
  const int* c_dst  = (const int*)d_in[7];
  const void* W_pa  = d_in[8];
  const void* b_pa  = d_in[9];
  const void* W_pp  = d_in[10];
  const void* b_pp  = d_in[11];
  const void* at_s_w  = d_in[12];
  const void* at_d_w  = d_in[13];
  const void* at_s_wb = d_in[14];
  const void* at_d_wb = d_in[15];
  const void* at_s_c  = d_in[16];
  const void* at_d_c  = d_in[17];
  const void* W_k   = d_in[18];
  const void* b_k   = d_in[19];
  const void* q     = d_in[20];
  const void* W_lin = d_in[21];
  const void* b_lin = d_in[22];

  // ---- workspace layout ----
  char* ws = (char*)d_ws;
  size_t off = 0;
  auto alloc = [&](size_t bytes) -> void* {
    void* p = ws + off;
    off += (bytes + 255) & ~(size_t)255;
    return p;
  };
  int*   flag_f = (int*)alloc(4);
  int*   flag_i = (int*)alloc(4);
  float* attn   = (float*)alloc(8 * 4);
  float* S      = (float*)alloc(2 * HID * 4);
  u16*   h_a    = (u16*)alloc((size_t)NA * HID * 2);
  u16*   h_p    = (u16*)alloc((size_t)NP * HID * 2);
  float* aA_ws  = (float*)alloc((size_t)NA * HEADS * 4);
  float* aA_wbd = (float*)alloc((size_t)NA * HEADS * 4);
  float* aP_wd  = (float*)alloc((size_t)NP * HEADS * 4);
  float* aP_wbs = (float*)alloc((size_t)NP * HEADS * 4);
  float* aP_cs  = (float*)alloc((size_t)NP * HEADS * 4);
  float* aP_cd  = (float*)alloc((size_t)NP * HEADS * 4);
  u16*   Pw16   = (u16*)alloc((size_t)NP * OUT_F * 2);
  u16*   Pc16   = (u16*)alloc((size_t)NP * OUT_F * 2);
  // per-type CSR buffers (deg blocks contiguous for one memset)
  int*   deg3   = (int*)alloc(((size_t)NP + NA + NP) * 4);
  int*   degW   = deg3;
  int*   degWB  = deg3 + NP;
  int*   degC   = deg3 + NP + NA;
  int*   rpW    = (int*)alloc(((size_t)NP + 1) * 4);
  int*   rpWB   = (int*)alloc(((size_t)NA + 1) * 4);
  int*   rpC    = (int*)alloc(((size_t)NP + 1) * 4);
  int*   curW   = (int*)alloc((size_t)NP * 4);
  int*   curWB  = (int*)alloc((size_t)NA * 4);
  int*   curC   = (int*)alloc((size_t)NP * 4);
  int*   bsW    = (int*)alloc(1024);
  int*   bsWB   = (int*)alloc(1024);
  int*   bsC    = (int*)alloc(1024);
  int*   csW    = (int*)alloc((size_t)E_w * 4);
  int*   csWB   = (int*)alloc((size_t)E_wb * 4);
  int*   csC    = (int*)alloc((size_t)E_c * 4);
  u16*   o16    = (u16*)(ws + off);             // rest of ws, chunked, bf16
  size_t o_bytes = (ws_size > off) ? (ws_size - off) : 0;
  long long cap = (long long)(o_bytes / ((size_t)HID * 2));
  int rc = (int)(cap > NP ? NP : cap);
  rc &= ~63;
  if (rc < 64) rc = 64;

  // ---- detection ----
  detect_float_width<<<1, 256, 0, stream>>>((const u16*)x_a, 4096, flag_f);
  detect_idx_width<<<1, 256, 0, stream>>>(w_src, 512, flag_i);

  // ---- projections + logits ----
  {
    int gA = (NA + 63) / 64; if (gA > 1024) gA = 1024;
    int gP = (NP + 63) / 64; if (gP > 1024) gP = 1024;
    proj_mfma<<<gA, 256, 0, stream>>>(x_a, W_pa, b_pa, h_a, NA, flag_f);
    proj_mfma<<<gP, 256, 0, stream>>>(x_p, W_pp, b_pp, h_p, NP, flag_f);
  }
  compute_a2<<<(NA * HEADS + 255) / 256, 256, 0, stream>>>(h_a, at_s_w, at_d_wb, aA_ws, aA_wbd, NA, flag_f);
  compute_a4<<<(NP * HEADS + 255) / 256, 256, 0, stream>>>(
      h_p, at_d_w, at_s_wb, at_s_c, at_d_c, aP_wd, aP_wbs, aP_cs, aP_cd, NP, flag_f);

  hipMemsetAsync(S, 0, 2 * HID * 4, stream);

  // ---- CSR build (hist merged, XCD-partitioned reorders) ----
  hipMemsetAsync(deg3, 0, ((size_t)NP + NA + NP) * 4, stream);
  {
    long long Etot = (long long)E_w + E_wb + E_c;
    hist3_kernel<<<(Etot + 255) / 256, 256, 0, stream>>>(
        w_dst, E_w, NP, degW, wb_dst, E_wb, NA, degWB, c_dst, E_c, NP, degC, flag_i);
    int nbW = (NP + 1023) / 1024, nbWB = (NA + 1023) / 1024, nbC = (NP + 1023) / 1024;
    scan1_kernel<<<nbW, 256, 0, stream>>>(degW, NP, rpW, bsW);
    scan1_kernel<<<nbWB, 256, 0, stream>>>(degWB, NA, rpWB, bsWB);
    scan1_kernel<<<nbC, 256, 0, stream>>>(degC, NP, rpC, bsC);
    scan2x3_kernel<<<1, 64, 0, stream>>>(bsW, nbW, bsWB, nbWB, bsC, nbC);
    scan3_kernel<<<(NP + 255) / 256, 256, 0, stream>>>(rpW, curW, bsW, NP, E_w);
    scan3_kernel<<<(NA + 255) / 256, 256, 0, stream>>>(rpWB, curWB, bsWB, NA, E_wb);
    scan3_kernel<<<(NP + 255) / 256, 256, 0, stream>>>(rpC, curC, bsC, NP, E_c);
    reorder_part<<<1024, 256, 0, stream>>>(w_src, w_dst, E_w, flag_i, NA, NP, curW, csW);
    reorder_part<<<1024, 256, 0, stream>>>(wb_src, wb_dst, E_wb, flag_i, NP, NA, curWB, csWB);
    reorder_part<<<1024, 256, 0, stream>>>(c_src, c_dst, E_c, flag_i, NP, NP, curC, csC);
  }

  // ---- writtenby: paper -> author (direct author output) ----
  for (int lo = 0; lo < NA; lo += rc) {
    int rows = (NA - lo < rc) ? (NA - lo) : rc;
    gather_conv<<<(rows + 3) / 4, 256, 0, stream>>>(rpWB, csWB, aP_wbs, aA_wbd, h_p, o16, lo, rows);
    int g = (rows + 63) / 64; if (g > 1024) g = 1024;
    author_mfma<<<g, 256, 0, stream>>>(o16, rows, lo, W_lin, b_lin, d_out, flag_f);
  }

  // ---- writes: author -> paper (S0 colsum + Pw) ----
  for (int lo = 0; lo < NP; lo += rc) {
    int rows = (NP - lo < rc) ? (NP - lo) : rc;
    gather_conv<<<(rows + 3) / 4, 256, 0, stream>>>(rpW, csW, aA_ws, aP_wd, h_a, o16, lo, rows);
    int g = (rows + 63) / 64; if (g > 1024) g = 1024;
    colsum_mfma<<<g, 256, 0, stream>>>(o16, rows, W_k, b_k, S, flag_f);
    linW_mfma<<<g, 256, 0, stream>>>(o16, rows, W_lin, Pw16 + (size_t)lo * OUT_F, flag_f);
  }

  // ---- cites: paper -> paper (S1 colsum + Pc) ----
  for (int lo = 0; lo < NP; lo += rc) {
    int rows = (NP - lo < rc) ? (NP - lo) : rc;
    gather_conv<<<(rows + 3) / 4, 256, 0, stream>>>(rpC, csC, aP_cs, aP_cd, h_p, o16, lo, rows);
    int g = (rows + 63) / 64; if (g > 1024) g = 1024;
    colsum_mfma<<<g, 256, 0, stream>>>(o16, rows, W_k, b_k, S + HID, flag_f);
    linW_mfma<<<g, 256, 0, stream>>>(o16, rows, W_lin, Pc16 + (size_t)lo * OUT_F, flag_f);
  }

  // ---- semantic softmax + paper output ----
  score_softmax<<<1, 64, 0, stream>>>(S, q, attn, 1.0f / (float)NP, flag_f);
  combine_paper<<<((size_t)NP * 16 + 255) / 256, 256, 0, stream>>>(Pw16, Pc16, attn, b_lin, d_out, (size_t)NA * OUT_F, NP, flag_f);
}

// Round 9
// 1184.752 us; speedup vs baseline: 1.1958x; 1.0028x over previous
//
#include <hip/hip_runtime.h>
#include <hip/hip_bf16.h>

// HANConv (HANModel). R9: apply the R8-proven XCD-partition cure to the
// histogram. hist3_part: 8 block-groups scan all 3 dst lists, atomicAdd
// only their own dst partition -> deg lines dirty in ONE XCD's L2 (R8
// counters: hist3 had 93MB HBM writes for 2MB payload, 45x amplification,
// same mechanism reorder had). Also merge the 3 reorder_part launches
// into one reorder3_part. All else identical to the measured-1188 R8.

#define HEADS 4
#define DH 32
#define HID 128
#define IN_F 128
#define OUT_F 64
#define NEG 0.2f

typedef unsigned short u16;
typedef unsigned int u32;
typedef __attribute__((ext_vector_type(8))) short short8;
typedef __attribute__((ext_vector_type(4))) float f32x4;

__device__ __forceinline__ float us2f(u16 u){ return __uint_as_float(((u32)u) << 16); }
__device__ __forceinline__ u16 f2us(float f){            // f32 -> bf16 RNE
  u32 u = __float_as_uint(f);
  u += 0x7fffu + ((u >> 16) & 1u);
  return (u16)(u >> 16);
}
__device__ __forceinline__ float fin(float v){ return (fabsf(v) < 1e30f) ? v : 0.f; }
__device__ __forceinline__ u16 san16(u16 r){ return (((r >> 7) & 0xff) == 0xff) ? (u16)0 : r; }
// fast tanh via exp2-backed __expf; clamp keeps (t-1)/(t+1) finite.
__device__ __forceinline__ float ftanh(float x){
  float t = __expf(fminf(fmaxf(2.f * x, -30.f), 30.f));
  return __fdividef(t - 1.f, t + 1.f);
}
// width-adaptive sanitized loads from raw input tensors
__device__ __forceinline__ float ldf(const void* p, size_t i, int wide){
  float v = wide ? ((const float*)p)[i] : us2f(((const u16*)p)[i]);
  return fin(v);
}
__device__ __forceinline__ u16 ld16(const void* p, size_t i, int wide){
  if (wide) return f2us(fin(((const float*)p)[i]));
  return san16(((const u16*)p)[i]);
}
__device__ __forceinline__ int ld_idx(const int* __restrict__ p, int e, int sh, int n){
  int v = p[(size_t)e << sh];
  return v < 0 ? 0 : (v >= n ? n - 1 : v);
}

// ---- detection kernels -----------------------------------------------------
__global__ void detect_float_width(const u16* __restrict__ x, int n, int* __restrict__ flag)
{
  __shared__ int cnt;
  if (threadIdx.x == 0) cnt = 0;
  __syncthreads();
  int local = 0;
  for (int i = threadIdx.x; i < n; i += blockDim.x) {
    int e = (x[i] >> 7) & 0xff;
    if (e == 0 || (e >= 100 && e <= 150)) local++;
  }
  atomicAdd(&cnt, local);
  __syncthreads();
  if (threadIdx.x == 0) *flag = (cnt < (n * 9) / 10) ? 1 : 0;  // 1 = f32
}
__global__ void detect_idx_width(const int* __restrict__ s, int n, int* __restrict__ flag)
{
  __shared__ int any;
  if (threadIdx.x == 0) any = 0;
  __syncthreads();
  for (int i = threadIdx.x; i < n; i += blockDim.x)
    if (s[2 * i + 1] != 0) atomicOr(&any, 1);
  __syncthreads();
  if (threadIdx.x == 0) *flag = any ? 0 : 1;                   // 1 = int64
}

// ---- MFMA GEMM infrastructure ---------------------------------------------
// B staged transposed in LDS: Bt[c][k] bf16, row stride 256B, XOR-swizzle
// byte ^= (c&7)<<4 so 16-lane column-slice ds_read_b128 is ~conflict-free.
template<int NC>
__device__ __forceinline__ void stage_B1(const void* W1, int wide, u16* Bt)
{
  for (int i = threadIdx.x; i < 128 * NC; i += 256) {
    int k = i / NC, c = i - k * NC;
    u16 v = ld16(W1, (size_t)k * NC + c, wide);
    u32 boff = ((u32)c << 8) + (((u32)(k << 1)) ^ (((u32)(c & 7)) << 4));
    *(u16*)((char*)Bt + boff) = v;
  }
}

// B fragment for tile t, k-step kk: lane c=(t*16+(l&15)), 8 bf16 k-contiguous
__device__ __forceinline__ short8 ldsB(const u16* Bt, int t, int lane, int kk)
{
  const int c = (t << 4) + (lane & 15);
  const u32 boff = ((u32)c << 8) +
      (((u32)(((lane >> 4) << 4) + (kk << 6))) ^ (((u32)(c & 7)) << 4));
  return *(const short8*)((const char*)Bt + boff);
}

// A fragment from raw input x (runtime f32/bf16), row rb, 8 k-contiguous bf16
__device__ __forceinline__ short8 ldA_x(const void* x, size_t rb, int kg, int kk, int wide)
{
  short8 v;
  const size_t base = rb + (size_t)(kg * 8 + kk * 32);
  if (wide) {
    const float* p = (const float*)x + base;
    const float4 f0 = *(const float4*)p;
    const float4 f1 = *(const float4*)(p + 4);
    v[0] = (short)f2us(fin(f0.x)); v[1] = (short)f2us(fin(f0.y));
    v[2] = (short)f2us(fin(f0.z)); v[3] = (short)f2us(fin(f0.w));
    v[4] = (short)f2us(fin(f1.x)); v[5] = (short)f2us(fin(f1.y));
    v[6] = (short)f2us(fin(f1.z)); v[7] = (short)f2us(fin(f1.w));
  } else {
    const short8 raw = *(const short8*)((const u16*)x + base);
#pragma unroll
    for (int j = 0; j < 8; ++j) v[j] = (short)san16((u16)raw[j]);
  }
  return v;
}

// A fragment from our clean bf16 o buffer
__device__ __forceinline__ short8 ldA_o(const u16* o, size_t rb, int kg, int kk)
{
  return *(const short8*)(o + rb + (size_t)(kg * 8 + kk * 32));
}

// ---- projection: h[n,c] = bf16(x[n,:] @ W[:,c] + b[c]) ---------------------
__global__ __launch_bounds__(256, 2) void proj_mfma(
    const void* __restrict__ x, const void* __restrict__ W,
    const void* __restrict__ b, u16* __restrict__ h, int N,
    const int* __restrict__ flag_f)
{
  const int wide = *flag_f;
  __shared__ u16 Bt[128 * 128];   // 32 KB
  stage_B1<HID>(W, wide, Bt);
  __syncthreads();
  const int w = threadIdx.x >> 6, lane = threadIdx.x & 63;
  const int r16 = lane & 15, kg = lane >> 4;
  float bv[8];
#pragma unroll
  for (int t = 0; t < 8; ++t) bv[t] = ldf(b, (t << 4) + r16, wide);
  const int nstrips = (N + 63) >> 6;
  for (int sidx = blockIdx.x; sidx < nstrips; sidx += gridDim.x) {
    const int rowbase = (sidx << 6) + (w << 4);
    int arow = rowbase + r16;
    if (arow >= N) arow = N - 1;
    const size_t rb = (size_t)arow * IN_F;
    f32x4 acc[8];
#pragma unroll
    for (int t = 0; t < 8; ++t) acc[t] = (f32x4){0.f, 0.f, 0.f, 0.f};
#pragma unroll
    for (int kk = 0; kk < 4; ++kk) {
      const short8 a = ldA_x(x, rb, kg, kk, wide);
#pragma unroll
      for (int t = 0; t < 8; ++t)
        acc[t] = __builtin_amdgcn_mfma_f32_16x16x32_bf16(a, ldsB(Bt, t, lane, kk), acc[t], 0, 0, 0);
    }
#pragma unroll
    for (int t = 0; t < 8; ++t) {
      const int col = (t << 4) + r16;
#pragma unroll
      for (int j = 0; j < 4; ++j) {
        const int row = rowbase + (kg << 2) + j;
        if (row < N) h[(size_t)row * HID + col] = f2us(acc[t][j] + bv[t]);
      }
    }
  }
}

// ---- colsum: S[c] += sum_n ftanh(o(relu'd bf16) @ Wk + bk) -----------------
__global__ __launch_bounds__(256, 2) void colsum_mfma(
    const u16* __restrict__ o, int rows, const void* __restrict__ Wk,
    const void* __restrict__ bk, float* __restrict__ S,
    const int* __restrict__ flag_f)
{
  const int wide = *flag_f;
  __shared__ u16 Bt[128 * 128];   // 32 KB
  __shared__ float sred[4][HID];  // 2 KB
  stage_B1<HID>(Wk, wide, Bt);
  __syncthreads();
  const int w = threadIdx.x >> 6, lane = threadIdx.x & 63;
  const int r16 = lane & 15, kg = lane >> 4;
  float bkv[8];
#pragma unroll
  for (int t = 0; t < 8; ++t) bkv[t] = ldf(bk, (t << 4) + r16, wide);
  float scs[8] = {0.f, 0.f, 0.f, 0.f, 0.f, 0.f, 0.f, 0.f};
  const int nstrips = (rows + 63) >> 6;
  for (int sidx = blockIdx.x; sidx < nstrips; sidx += gridDim.x) {
    const int rowbase = (sidx << 6) + (w << 4);
    int arow = rowbase + r16;
    if (arow >= rows) arow = rows - 1;
    const size_t rb = (size_t)arow * HID;
    f32x4 acc[8];
#pragma unroll
    for (int t = 0; t < 8; ++t) acc[t] = (f32x4){0.f, 0.f, 0.f, 0.f};
#pragma unroll
    for (int kk = 0; kk < 4; ++kk) {
      const short8 a = ldA_o(o, rb, kg, kk);
#pragma unroll
      for (int t = 0; t < 8; ++t)
        acc[t] = __builtin_amdgcn_mfma_f32_16x16x32_bf16(a, ldsB(Bt, t, lane, kk), acc[t], 0, 0, 0);
    }
#pragma unroll
    for (int t = 0; t < 8; ++t) {
#pragma unroll
      for (int j = 0; j < 4; ++j) {
        const int row = rowbase + (kg << 2) + j;
        if (row < rows) scs[t] += ftanh(acc[t][j] + bkv[t]);
      }
    }
  }
  // reduce: kg-groups share a column -> shfl over kg -> per-wave row -> atomic
#pragma unroll
  for (int t = 0; t < 8; ++t) {
    float v = scs[t];
    v += __shfl_xor(v, 16);
    v += __shfl_xor(v, 32);
    if (kg == 0) sred[w][(t << 4) + r16] = v;
  }
  __syncthreads();
  if (threadIdx.x < HID) {
    float v = sred[0][threadIdx.x] + sred[1][threadIdx.x] +
              sred[2][threadIdx.x] + sred[3][threadIdx.x];
    atomicAdd(&S[threadIdx.x], v);
  }
}

// ---- P = o(relu'd bf16) @ Wlin  (no bias) -> bf16 --------------------------
__global__ __launch_bounds__(256, 2) void linW_mfma(
    const u16* __restrict__ o, int rows, const void* __restrict__ Wlin,
    u16* __restrict__ P, const int* __restrict__ flag_f)
{
  const int wide = *flag_f;
  __shared__ u16 Bt[64 * 128];    // 16 KB
  stage_B1<OUT_F>(Wlin, wide, Bt);
  __syncthreads();
  const int w = threadIdx.x >> 6, lane = threadIdx.x & 63;
  const int r16 = lane & 15, kg = lane >> 4;
  const int nstrips = (rows + 63) >> 6;
  for (int sidx = blockIdx.x; sidx < nstrips; sidx += gridDim.x) {
    const int rowbase = (sidx << 6) + (w << 4);
    int arow = rowbase + r16;
    if (arow >= rows) arow = rows - 1;
    const size_t rb = (size_t)arow * HID;
    f32x4 acc[4];
#pragma unroll
    for (int t = 0; t < 4; ++t) acc[t] = (f32x4){0.f, 0.f, 0.f, 0.f};
#pragma unroll
    for (int kk = 0; kk < 4; ++kk) {
      const short8 a = ldA_o(o, rb, kg, kk);
#pragma unroll
      for (int t = 0; t < 4; ++t)
        acc[t] = __builtin_amdgcn_mfma_f32_16x16x32_bf16(a, ldsB(Bt, t, lane, kk), acc[t], 0, 0, 0);
    }
#pragma unroll
    for (int t = 0; t < 4; ++t) {
      const int col = (t << 4) + r16;
#pragma unroll
      for (int j = 0; j < 4; ++j) {
        const int row = rowbase + (kg << 2) + j;
        if (row < rows) P[(size_t)row * OUT_F + col] = f2us(acc[t][j]);
      }
    }
  }
}

// ---- author out: y = o(bf16,relu'd) @ Wlin + blin  (width-adaptive) --------
__global__ __launch_bounds__(256, 2) void author_mfma(
    const u16* __restrict__ o, int rows, int node0,
    const void* __restrict__ Wlin, const void* __restrict__ blin,
    void* __restrict__ out, const int* __restrict__ flag_f)
{
  const int wide = *flag_f;
  __shared__ u16 Bt[64 * 128];    // 16 KB
  stage_B1<OUT_F>(Wlin, wide, Bt);
  __syncthreads();
  const int w = threadIdx.x >> 6, lane = threadIdx.x & 63;
  const int r16 = lane & 15, kg = lane >> 4;
  float bv[4];
#pragma unroll
  for (int t = 0; t < 4; ++t) bv[t] = ldf(blin, (t << 4) + r16, wide);
  const int nstrips = (rows + 63) >> 6;
  for (int sidx = blockIdx.x; sidx < nstrips; sidx += gridDim.x) {
    const int rowbase = (sidx << 6) + (w << 4);
    int arow = rowbase + r16;
    if (arow >= rows) arow = rows - 1;
    const size_t rb = (size_t)arow * HID;
    f32x4 acc[4];
#pragma unroll
    for (int t = 0; t < 4; ++t) acc[t] = (f32x4){0.f, 0.f, 0.f, 0.f};
#pragma unroll
    for (int kk = 0; kk < 4; ++kk) {
      const short8 a = ldA_o(o, rb, kg, kk);
#pragma unroll
      for (int t = 0; t < 4; ++t)
        acc[t] = __builtin_amdgcn_mfma_f32_16x16x32_bf16(a, ldsB(Bt, t, lane, kk), acc[t], 0, 0, 0);
    }
#pragma unroll
    for (int t = 0; t < 4; ++t) {
      const int col = (t << 4) + r16;
#pragma unroll
      for (int j = 0; j < 4; ++j) {
        const int row = rowbase + (kg << 2) + j;
        if (row < rows) {
          const float val = acc[t][j] + bv[t];
          const size_t oi = (size_t)(node0 + row) * OUT_F + col;
          if (wide) ((float*)out)[oi] = val;
          else      ((u16*)out)[oi] = f2us(val);
        }
      }
    }
  }
}

// ---- per-node logits: 2 att vectors (author h) -----------------------------
__global__ __launch_bounds__(256) void compute_a2(
    const u16* __restrict__ h, const void* __restrict__ att1,
    const void* __restrict__ att2, float* __restrict__ a1,
    float* __restrict__ a2, int N, const int* __restrict__ flag_f)
{
  const int wide = *flag_f;
  __shared__ float s1[HID], s2[HID];
  if (threadIdx.x < HID) {
    s1[threadIdx.x] = ldf(att1, threadIdx.x, wide);
    s2[threadIdx.x] = ldf(att2, threadIdx.x, wide);
  }
  __syncthreads();
  int t = blockIdx.x * 256 + threadIdx.x;
  if (t >= N * HEADS) return;
  int n = t >> 2, hh = t & 3;
  const u16* p = h + (size_t)n * HID + hh * DH;
  float acc1 = 0.f, acc2 = 0.f;
#pragma unroll
  for (int d = 0; d < DH; ++d) {
    float f = us2f(p[d]);
    acc1 += f * s1[hh * DH + d];
    acc2 += f * s2[hh * DH + d];
  }
  a1[t] = fin(acc1);
  a2[t] = fin(acc2);
}

// ---- per-node logits: 4 att vectors, ONE h read (paper h) ------------------
__global__ __launch_bounds__(256) void compute_a4(
    const u16* __restrict__ h,
    const void* __restrict__ att1, const void* __restrict__ att2,
    const void* __restrict__ att3, const void* __restrict__ att4,
    float* __restrict__ a1, float* __restrict__ a2,
    float* __restrict__ a3, float* __restrict__ a4,
    int N, const int* __restrict__ flag_f)
{
  const int wide = *flag_f;
  __shared__ float s1[HID], s2[HID], s3[HID], s4[HID];
  if (threadIdx.x < HID) {
    s1[threadIdx.x] = ldf(att1, threadIdx.x, wide);
    s2[threadIdx.x] = ldf(att2, threadIdx.x, wide);
    s3[threadIdx.x] = ldf(att3, threadIdx.x, wide);
    s4[threadIdx.x] = ldf(att4, threadIdx.x, wide);
  }
  __syncthreads();
  int t = blockIdx.x * 256 + threadIdx.x;
  if (t >= N * HEADS) return;
  int n = t >> 2, hh = t & 3;
  const u16* p = h + (size_t)n * HID + hh * DH;
  float acc1 = 0.f, acc2 = 0.f, acc3 = 0.f, acc4 = 0.f;
#pragma unroll
  for (int d = 0; d < DH; ++d) {
    float f = us2f(p[d]);
    int c = hh * DH + d;
    acc1 += f * s1[c];
    acc2 += f * s2[c];
    acc3 += f * s3[c];
    acc4 += f * s4[c];
  }
  a1[t] = fin(acc1);
  a2[t] = fin(acc2);
  a3[t] = fin(acc3);
  a4[t] = fin(acc4);
}

// ---- CSR build -------------------------------------------------------------
// XCD-partitioned histogram: 8 block-groups (part = blockIdx&7) scan all 3
// dst lists; each group only atomicAdds dsts in its partition -> each deg
// line is dirty in ONE XCD's L2 (kills the 45x write amplification measured
// in R8: 93MB HBM writes for 2MB payload). Exact under any block mapping.
__global__ __launch_bounds__(256) void hist3_part(
    const int* __restrict__ d0, int E0, int N0, int* __restrict__ g0,
    const int* __restrict__ d1, int E1, int N1, int* __restrict__ g1,
    const int* __restrict__ d2, int E2, int N2, int* __restrict__ g2,
    const int* __restrict__ flag_i)
{
  const int part = blockIdx.x & 7;
  const int grp  = blockIdx.x >> 3;
  const int ngrp = gridDim.x >> 3;
  const int sh = *flag_i;
  for (int e = grp * 256 + threadIdx.x; e < E0; e += ngrp * 256) {
    int d = ld_idx(d0, e, sh, N0);
    if ((d * 8) / N0 == part) atomicAdd(&g0[d], 1);
  }
  for (int e = grp * 256 + threadIdx.x; e < E1; e += ngrp * 256) {
    int d = ld_idx(d1, e, sh, N1);
    if ((d * 8) / N1 == part) atomicAdd(&g1[d], 1);
  }
  for (int e = grp * 256 + threadIdx.x; e < E2; e += ngrp * 256) {
    int d = ld_idx(d2, e, sh, N2);
    if ((d * 8) / N2 == part) atomicAdd(&g2[d], 1);
  }
}

__global__ __launch_bounds__(256) void scan1_kernel(
    const int* __restrict__ deg, int Nd, int* __restrict__ rowptr,
    int* __restrict__ blksum)
{
  __shared__ int ssum[256];
  int base = blockIdx.x * 1024;
  int t = threadIdx.x;
  int idx0 = base + t * 4;
  int v[4];
#pragma unroll
  for (int j = 0; j < 4; ++j) v[j] = (idx0 + j < Nd) ? deg[idx0 + j] : 0;
  int tsum = v[0] + v[1] + v[2] + v[3];
  ssum[t] = tsum;
  __syncthreads();
  for (int ofs = 1; ofs < 256; ofs <<= 1) {
    int x = (t >= ofs) ? ssum[t - ofs] : 0;
    __syncthreads();
    ssum[t] += x;
    __syncthreads();
  }
  if (t == 255) blksum[blockIdx.x] = ssum[255];
  int run = ssum[t] - tsum;
#pragma unroll
  for (int j = 0; j < 4; ++j) {
    if (idx0 + j < Nd) rowptr[idx0 + j] = run;
    run += v[j];
  }
}

// three independent tiny serial scans, one launch
__global__ void scan2x3_kernel(int* __restrict__ b0, int n0,
                               int* __restrict__ b1, int n1,
                               int* __restrict__ b2, int n2)
{
  if (blockIdx.x == 0) {
    if (threadIdx.x == 0) { int r = 0; for (int i = 0; i < n0; ++i) { int t = b0[i]; b0[i] = r; r += t; } }
    if (threadIdx.x == 1) { int r = 0; for (int i = 0; i < n1; ++i) { int t = b1[i]; b1[i] = r; r += t; } }
    if (threadIdx.x == 2) { int r = 0; for (int i = 0; i < n2; ++i) { int t = b2[i]; b2[i] = r; r += t; } }
  }
}

__global__ __launch_bounds__(256) void scan3_kernel(
    int* __restrict__ rowptr, int* __restrict__ cursor,
    const int* __restrict__ blksum, int Nd, int E)
{
  int i = blockIdx.x * 256 + threadIdx.x;
  if (i < Nd) {
    int v = rowptr[i] + blksum[i >> 10];
    rowptr[i] = v;
    cursor[i] = v;
  }
  if (i == 0) rowptr[Nd] = E;
}

// XCD-partitioned reorder over all 3 edge types in one launch.
__global__ __launch_bounds__(256) void reorder3_part(
    const int* __restrict__ s0, const int* __restrict__ d0, int E0, int Ns0, int N0,
    int* __restrict__ c0, int* __restrict__ o0,
    const int* __restrict__ s1, const int* __restrict__ d1, int E1, int Ns1, int N1,
    int* __restrict__ c1, int* __restrict__ o1,
    const int* __restrict__ s2, const int* __restrict__ d2, int E2, int Ns2, int N2,
    int* __restrict__ c2, int* __restrict__ o2,
    const int* __restrict__ flag_i)
{
  const int part = blockIdx.x & 7;
  const int grp  = blockIdx.x >> 3;
  const int ngrp = gridDim.x >> 3;
  const int sh = *flag_i;
  for (int e = grp * 256 + threadIdx.x; e < E0; e += ngrp * 256) {
    int d = ld_idx(d0, e, sh, N0);
    if ((d * 8) / N0 == part) {
      int s = ld_idx(s0, e, sh, Ns0);
      o0[atomicAdd(&c0[d], 1)] = s;
    }
  }
  for (int e = grp * 256 + threadIdx.x; e < E1; e += ngrp * 256) {
    int d = ld_idx(d1, e, sh, N1);
    if ((d * 8) / N1 == part) {
      int s = ld_idx(s1, e, sh, Ns1);
      o1[atomicAdd(&c1[d], 1)] = s;
    }
  }
  for (int e = grp * 256 + threadIdx.x; e < E2; e += ngrp * 256) {
    int d = ld_idx(d2, e, sh, N2);
    if ((d * 8) / N2 == part) {
      int s = ld_idx(s2, e, sh, Ns2);
      o2[atomicAdd(&c2[d], 1)] = s;
    }
  }
}

// ---- gather edge conv: one wave per dst node, lane = 2 channels ------------
// SINGLE pass, branchless online softmax (running max + rescale).
__global__ __launch_bounds__(256) void gather_conv(
    const int* __restrict__ rowptr, const int* __restrict__ csr_src,
    const float* __restrict__ a_s, const float* __restrict__ a_d,
    const u16* __restrict__ h_src, u16* __restrict__ o,
    int lo, int rows)
{
  int wid = (blockIdx.x * 256 + threadIdx.x) >> 6;
  if (wid >= rows) return;
  int n = lo + wid;
  int lane = threadIdx.x & 63;
  int hh = lane >> 4;
  int start = rowptr[n], end = rowptr[n + 1];
  float ad = a_d[(size_t)n * HEADS + hh];
  float m = -1e30f, den = 0.f, n0 = 0.f, n1 = 0.f;
  int e = start;
  for (; e + 4 <= end; e += 4) {
    int s0 = csr_src[e],     s1 = csr_src[e + 1];
    int s2 = csr_src[e + 2], s3 = csr_src[e + 3];
    float x0 = a_s[(size_t)s0 * HEADS + hh] + ad;
    float x1 = a_s[(size_t)s1 * HEADS + hh] + ad;
    float x2 = a_s[(size_t)s2 * HEADS + hh] + ad;
    float x3 = a_s[(size_t)s3 * HEADS + hh] + ad;
    ushort2 h0 = *(const ushort2*)(h_src + (size_t)s0 * HID + 2 * lane);
    ushort2 h1 = *(const ushort2*)(h_src + (size_t)s1 * HID + 2 * lane);
    ushort2 h2 = *(const ushort2*)(h_src + (size_t)s2 * HID + 2 * lane);
    ushort2 h3 = *(const ushort2*)(h_src + (size_t)s3 * HID + 2 * lane);
    x0 = (x0 > 0.f) ? x0 : NEG * x0;
    x1 = (x1 > 0.f) ? x1 : NEG * x1;
    x2 = (x2 > 0.f) ? x2 : NEG * x2;
    x3 = (x3 > 0.f) ? x3 : NEG * x3;
    float mloc = fmaxf(fmaxf(x0, x1), fmaxf(x2, x3));
    float mn = fmaxf(m, mloc);
    float sc = __expf(m - mn);           // 0 on first batch, 1 if max unchanged
    float e0 = __expf(x0 - mn), e1 = __expf(x1 - mn);
    float e2 = __expf(x2 - mn), e3 = __expf(x3 - mn);
    den = den * sc + ((e0 + e1) + (e2 + e3));
    n0  = n0 * sc + (e0 * us2f(h0.x) + e1 * us2f(h1.x))
                  + (e2 * us2f(h2.x) + e3 * us2f(h3.x));
    n1  = n1 * sc + (e0 * us2f(h0.y) + e1 * us2f(h1.y))
                  + (e2 * us2f(h2.y) + e3 * us2f(h3.y));
    m = mn;
  }
  for (; e < end; ++e) {
    int s = csr_src[e];
    float x = a_s[(size_t)s * HEADS + hh] + ad;
    ushort2 hv = *(const ushort2*)(h_src + (size_t)s * HID + 2 * lane);
    x = (x > 0.f) ? x : NEG * x;
    float mn = fmaxf(m, x);
    float sc = __expf(m - mn);
    float ex = __expf(x - mn);
    den = den * sc + ex;
    n0  = n0 * sc + ex * us2f(hv.x);
    n1  = n1 * sc + ex * us2f(hv.y);
    m = mn;
  }
  float inv = 1.f / (den + 1e-16f);
  ushort2 st;
  st.x = f2us(fmaxf(n0 * inv, 0.f));
  st.y = f2us(fmaxf(n1 * inv, 0.f));
  *(ushort2*)(o + (size_t)wid * HID + 2 * lane) = st;
}

// ---- semantic softmax ------------------------------------------------------
__global__ void score_softmax(const float* __restrict__ S, const void* __restrict__ q,
                              float* __restrict__ attn, float invN,
                              const int* __restrict__ flag_f)
{
  if (threadIdx.x == 0 && blockIdx.x == 0) {
    const int wide = *flag_f;
    float s0 = 0.f, s1 = 0.f;
    for (int c = 0; c < HID; ++c) {
      float qc = ldf(q, c, wide);
      s0 += qc * S[c] * invN;
      s1 += qc * S[HID + c] * invN;
    }
    float m = fmaxf(s0, s1);
    float e0 = __expf(s0 - m), e1 = __expf(s1 - m);
    attn[0] = e0 / (e0 + e1);
    attn[1] = e1 / (e0 + e1);
  }
}

// ---- paper out: y = a0*Pw + a1*Pc + blin  (elem_off = NA*OUT_F) ------------
__global__ __launch_bounds__(256) void combine_paper(
    const u16* __restrict__ Pw, const u16* __restrict__ Pc,
    const float* __restrict__ attn, const void* __restrict__ blin,
    void* __restrict__ out, size_t elem_off, int N,
    const int* __restrict__ flag_f)
{
  int t = blockIdx.x * 256 + threadIdx.x;
  if (t >= N * 16) return;
  const int wide = *flag_f;
  int n = t >> 4, cq = t & 15;
  const float a0 = attn[0], a1 = attn[1];
  size_t i = (size_t)n * OUT_F + cq * 4;
  ushort4 w4 = *(const ushort4*)&Pw[i];
  ushort4 c4 = *(const ushort4*)&Pc[i];
  float v[4];
  v[0] = a0 * us2f(w4.x) + a1 * us2f(c4.x) + ldf(blin, cq * 4 + 0, wide);
  v[1] = a0 * us2f(w4.y) + a1 * us2f(c4.y) + ldf(blin, cq * 4 + 1, wide);
  v[2] = a0 * us2f(w4.z) + a1 * us2f(c4.z) + ldf(blin, cq * 4 + 2, wide);
  v[3] = a0 * us2f(w4.w) + a1 * us2f(c4.w) + ldf(blin, cq * 4 + 3, wide);
  size_t oi = elem_off + i;
  if (wide) {
    float4 ov = {v[0], v[1], v[2], v[3]};
    *(float4*)&((float*)out)[oi] = ov;
  } else {
    ushort4 ov;
    ov.x = f2us(v[0]); ov.y = f2us(v[1]); ov.z = f2us(v[2]); ov.w = f2us(v[3]);
    *(ushort4*)&((u16*)out)[oi] = ov;
  }
}

// ---------------------------------------------------------------------------
extern "C" void kernel_launch(void* const* d_in, const int* in_sizes, int n_in,
                              void* d_out, int out_size, void* d_ws, size_t ws_size,
                              hipStream_t stream)
{
  const int NA = in_sizes[0] / IN_F;   // 100000
  const int NP = in_sizes[1] / IN_F;   // 200000
  const int E_w = in_sizes[2], E_wb = in_sizes[4], E_c = in_sizes[6];

  const void* x_a   = d_in[0];
  const void* x_p   = d_in[1];
  const int* w_src  = (const int*)d_in[2];
  const int* w_dst  = (const int*)d_in[3];
  const int* wb_src = (const int*)d_in[4];
  const int* wb_dst = (const int*)d_in[5];
  const int* c_src  = (const int*)d_in[6];
  const int* c_dst  = (const int*)d_in[7];
  const void* W_pa  = d_in[8];
  const void* b_pa  = d_in[9];
  const void* W_pp  = d_in[10];
  const void* b_pp  = d_in[11];
  const void* at_s_w  = d_in[12];
  const void* at_d_w  = d_in[13];
  const void* at_s_wb = d_in[14];
  const void* at_d_wb = d_in[15];
  const void* at_s_c  = d_in[16];
  const void* at_d_c  = d_in[17];
  const void* W_k   = d_in[18];
  const void* b_k   = d_in[19];
  const void* q     = d_in[20];
  const void* W_lin = d_in[21];
  const void* b_lin = d_in[22];

  // ---- workspace layout ----
  char* ws = (char*)d_ws;
  size_t off = 0;
  auto alloc = [&](size_t bytes) -> void* {
    void* p = ws + off;
    off += (bytes + 255) & ~(size_t)255;
    return p;
  };
  int*   flag_f = (int*)alloc(4);
  int*   flag_i = (int*)alloc(4);
  float* attn   = (float*)alloc(8 * 4);
  float* S      = (float*)alloc(2 * HID * 4);
  u16*   h_a    = (u16*)alloc((size_t)NA * HID * 2);
  u16*   h_p    = (u16*)alloc((size_t)NP * HID * 2);
  float* aA_ws  = (float*)alloc((size_t)NA * HEADS * 4);
  float* aA_wbd = (float*)alloc((size_t)NA * HEADS * 4);
  float* aP_wd  = (float*)alloc((size_t)NP * HEADS * 4);
  float* aP_wbs = (float*)alloc((size_t)NP * HEADS * 4);
  float* aP_cs  = (float*)alloc((size_t)NP * HEADS * 4);
  float* aP_cd  = (float*)alloc((size_t)NP * HEADS * 4);
  u16*   Pw16   = (u16*)alloc((size_t)NP * OUT_F * 2);
  u16*   Pc16   = (u16*)alloc((size_t)NP * OUT_F * 2);
  // per-type CSR buffers (deg blocks contiguous for one memset)
  int*   deg3   = (int*)alloc(((size_t)NP + NA + NP) * 4);
  int*   degW   = deg3;
  int*   degWB  = deg3 + NP;
  int*   degC   = deg3 + NP + NA;
  int*   rpW    = (int*)alloc(((size_t)NP + 1) * 4);
  int*   rpWB   = (int*)alloc(((size_t)NA + 1) * 4);
  int*   rpC    = (int*)alloc(((size_t)NP + 1) * 4);
  int*   curW   = (int*)alloc((size_t)NP * 4);
  int*   curWB  = (int*)alloc((size_t)NA * 4);
  int*   curC   = (int*)alloc((size_t)NP * 4);
  int*   bsW    = (int*)alloc(1024);
  int*   bsWB   = (int*)alloc(1024);
  int*   bsC    = (int*)alloc(1024);
  int*   csW    = (int*)alloc((size_t)E_w * 4);
  int*   csWB   = (int*)alloc((size_t)E_wb * 4);
  int*   csC    = (int*)alloc((size_t)E_c * 4);
  u16*   o16    = (u16*)(ws + off);             // rest of ws, chunked, bf16
  size_t o_bytes = (ws_size > off) ? (ws_size - off) : 0;
  long long cap = (long long)(o_bytes / ((size_t)HID * 2));
  int rc = (int)(cap > NP ? NP : cap);
  rc &= ~63;
  if (rc < 64) rc = 64;

  // ---- detection ----
  detect_float_width<<<1, 256, 0, stream>>>((const u16*)x_a, 4096, flag_f);
  detect_idx_width<<<1, 256, 0, stream>>>(w_src, 512, flag_i);

  // ---- projections + logits ----
  {
    int gA = (NA + 63) / 64; if (gA > 1024) gA = 1024;
    int gP = (NP + 63) / 64; if (gP > 1024) gP = 1024;
    proj_mfma<<<gA, 256, 0, stream>>>(x_a, W_pa, b_pa, h_a, NA, flag_f);
    proj_mfma<<<gP, 256, 0, stream>>>(x_p, W_pp, b_pp, h_p, NP, flag_f);
  }
  compute_a2<<<(NA * HEADS + 255) / 256, 256, 0, stream>>>(h_a, at_s_w, at_d_wb, aA_ws, aA_wbd, NA, flag_f);
  compute_a4<<<(NP * HEADS + 255) / 256, 256, 0, stream>>>(
      h_p, at_d_w, at_s_wb, at_s_c, at_d_c, aP_wd, aP_wbs, aP_cs, aP_cd, NP, flag_f);

  hipMemsetAsync(S, 0, 2 * HID * 4, stream);

  // ---- CSR build (XCD-partitioned hist + reorder) ----
  hipMemsetAsync(deg3, 0, ((size_t)NP + NA + NP) * 4, stream);
  {
    hist3_part<<<1024, 256, 0, stream>>>(
        w_dst, E_w, NP, degW, wb_dst, E_wb, NA, degWB, c_dst, E_c, NP, degC, flag_i);
    int nbW = (NP + 1023) / 1024, nbWB = (NA + 1023) / 1024, nbC = (NP + 1023) / 1024;
    scan1_kernel<<<nbW, 256, 0, stream>>>(degW, NP, rpW, bsW);
    scan1_kernel<<<nbWB, 256, 0, stream>>>(degWB, NA, rpWB, bsWB);
    scan1_kernel<<<nbC, 256, 0, stream>>>(degC, NP, rpC, bsC);
    scan2x3_kernel<<<1, 64, 0, stream>>>(bsW, nbW, bsWB, nbWB, bsC, nbC);
    scan3_kernel<<<(NP + 255) / 256, 256, 0, stream>>>(rpW, curW, bsW, NP, E_w);
    scan3_kernel<<<(NA + 255) / 256, 256, 0, stream>>>(rpWB, curWB, bsWB, NA, E_wb);
    scan3_kernel<<<(NP + 255) / 256, 256, 0, stream>>>(rpC, curC, bsC, NP, E_c);
    reorder3_part<<<1024, 256, 0, stream>>>(
        w_src, w_dst, E_w, NA, NP, curW, csW,
        wb_src, wb_dst, E_wb, NP, NA, curWB, csWB,
        c_src, c_dst, E_c, NP, NP, curC, csC, flag_i);
  }

  // ---- writtenby: paper -> author (direct author output) ----
  for (int lo = 0; lo < NA; lo += rc) {
    int rows = (NA - lo < rc) ? (NA - lo) : rc;
    gather_conv<<<(rows + 3) / 4, 256, 0, stream>>>(rpWB, csWB, aP_wbs, aA_wbd, h_p, o16, lo, rows);
    int g = (rows + 63) / 64; if (g > 1024) g = 1024;
    author_mfma<<<g, 256, 0, stream>>>(o16, rows, lo, W_lin, b_lin, d_out, flag_f);
  }

  // ---- writes: author -> paper (S0 colsum + Pw) ----
  for (int lo = 0; lo < NP; lo += rc) {
    int rows = (NP - lo < rc) ? (NP - lo) : rc;
    gather_conv<<<(rows + 3) / 4, 256, 0, stream>>>(rpW, csW, aA_ws, aP_wd, h_a, o16, lo, rows);
    int g = (rows + 63) / 64; if (g > 1024) g = 1024;
    colsum_mfma<<<g, 256, 0, stream>>>(o16, rows, W_k, b_k, S, flag_f);
    linW_mfma<<<g, 256, 0, stream>>>(o16, rows, W_lin, Pw16 + (size_t)lo * OUT_F, flag_f);
  }

  // ---- cites: paper -> paper (S1 colsum + Pc) ----
  for (int lo = 0; lo < NP; lo += rc) {
    int rows = (NP - lo < rc) ? (NP - lo) : rc;
    gather_conv<<<(rows + 3) / 4, 256, 0, stream>>>(rpC, csC, aP_cs, aP_cd, h_p, o16, lo, rows);
    int g = (rows + 63) / 64; if (g > 1024) g = 1024;
    colsum_mfma<<<g, 256, 0, stream>>>(o16, rows, W_k, b_k, S + HID, flag_f);
    linW_mfma<<<g, 256, 0, stream>>>(o16, rows, W_lin, Pc16 + (size_t)lo * OUT_F, flag_f);
  }

  // ---- semantic softmax + paper output ----
  score_softmax<<<1, 64, 0, stream>>>(S, q, attn, 1.0f / (float)NP, flag_f);
  combine_paper<<<((size_t)NP * 16 + 255) / 256, 256, 0, stream>>>(Pw16, Pc16, attn, b_lin, d_out, (size_t)NA * OUT_F, NP, flag_f);
}